// Round 3
// baseline (24012.268 us; speedup 1.0000x reference)
//
#include <hip/hip_runtime.h>

#define BB   8
#define HH   128
#define WW   200
#define HWSZ 25600            // HH*WW
#define C48  48
#define C64  64
#define NGRP 8
#define EPSV 1e-5f
#define LAMV 1e-4
#define SLOT 9830400          // BB*C48*HWSZ (one z/F/G slot, elements)
#define DPB  1228800          // C48*HWSZ (per-batch flat dim)
#define Y64SZ 13107200        // BB*C64*HWSZ
#define BIGELEMS 131072000ull // 12*SLOT + Y64SZ

// ---------------- bf16 storage helpers (compute always fp32) ----------------

typedef unsigned short bf16_t;

__device__ inline float b2f(bf16_t b) { return __uint_as_float(((unsigned)b) << 16); }
__device__ inline bf16_t f2b(float f) {           // round-to-nearest-even
    unsigned u = __float_as_uint(f);
    unsigned r = u + 0x7fffu + ((u >> 16) & 1u);
    return (bf16_t)(r >> 16);
}
__device__ inline float ldS(const float* p) { return *p; }
__device__ inline float ldS(const bf16_t* p) { return b2f(*p); }
__device__ inline float4 ld4(const float* p) { return *(const float4*)p; }
__device__ inline float4 ld4(const bf16_t* p) {
    ushort4 u = *(const ushort4*)p;
    return make_float4(b2f(u.x), b2f(u.y), b2f(u.z), b2f(u.w));
}
__device__ inline void st4(float* p, float4 v) { *(float4*)p = v; }
__device__ inline void st4(bf16_t* p, float4 v) {
    ushort4 u; u.x = f2b(v.x); u.y = f2b(v.y); u.z = f2b(v.z); u.w = f2b(v.w);
    *(ushort4*)p = u;
}

// ---------------- small utility kernels ----------------

__global__ void zero_kernel(float* __restrict__ p, int n) {
    int i = blockIdx.x * 256 + threadIdx.x;
    if (i < n) p[i] = 0.f;
}

__global__ void fill16_kernel(float4* __restrict__ p) {   // grid*256 16B chunks
    float4 z; z.x = z.y = z.z = z.w = 0.f;
    p[(size_t)blockIdx.x * 256 + threadIdx.x] = z;
}

__global__ void copy16_kernel(float4* __restrict__ dst, const float4* __restrict__ src) {
    size_t i = (size_t)blockIdx.x * 256 + threadIdx.x;
    dst[i] = src[i];
}

// f64 block reduction + one atomic per block (sum, sumsq)
__device__ inline void stats_reduce_atomic_d(double s, double q, double* red, double* dst) {
    #pragma unroll
    for (int off = 32; off > 0; off >>= 1) {
        s += __shfl_down(s, off);
        q += __shfl_down(q, off);
    }
    __syncthreads();
    if ((threadIdx.x & 63) == 0) { red[threadIdx.x >> 6] = s; red[4 + (threadIdx.x >> 6)] = q; }
    __syncthreads();
    if (threadIdx.x == 0) {
        atomicAdd(dst + 0, red[0] + red[1] + red[2] + red[3]);
        atomicAdd(dst + 1, red[4] + red[5] + red[6] + red[7]);
    }
}

// sums (f64 pairs) -> (mean, invstd) floats per pair
__global__ void finalize_kernel(const double* __restrict__ sums, float* __restrict__ msinv,
                                int npairs, double invcnt) {
    int i = blockIdx.x * 64 + threadIdx.x;
    if (i < npairs) {
        double s = sums[2 * i], q = sums[2 * i + 1];
        double mean = s * invcnt;
        double var = q * invcnt - mean * mean;
        double inv = 1.0 / sqrt(var + (double)EPSV);
        msinv[2 * i] = (float)mean;
        msinv[2 * i + 1] = (float)inv;
    }
}

// ---------------- conv0 (1->48) + BN stats (always fp32 in/out) ----------------

__global__ __launch_bounds__(256) void conv0_kernel(
    const float* __restrict__ x, const float* __restrict__ w,
    const float* __restrict__ bias, float* __restrict__ out,
    double* __restrict__ dstats)
{
    __shared__ double red[8];
    int idx = blockIdx.x * 256 + threadIdx.x;     // B*48*HW, exact multiple of 256
    int xw = idx % WW;
    int t  = idx / WW;
    int yh = t % HH; t /= HH;
    int c  = t % C48;
    int b  = t / C48;
    const float* __restrict__ xp = x + (size_t)b * HWSZ;
    const float* __restrict__ wc = w + c * 9;
    float acc = bias[c];
    #pragma unroll
    for (int dy = 0; dy < 3; dy++) {
        int gy = yh + dy - 1;
        if ((unsigned)gy >= (unsigned)HH) continue;
        #pragma unroll
        for (int dx = 0; dx < 3; dx++) {
            int gx = xw + dx - 1;
            if ((unsigned)gx >= (unsigned)WW) continue;
            acc = fmaf(xp[gy * WW + gx], wc[dy * 3 + dx], acc);
        }
    }
    out[idx] = acc;
    double dv = (double)acc;
    stats_reduce_atomic_d(dv, dv * dv, red, dstats + (size_t)c * 2);  // pair = channel
}

// BN apply: raw fp32 -> h (T storage)
template<typename TO>
__global__ __launch_bounds__(256) void bn_apply_kernel(
    const float* __restrict__ src, TO* __restrict__ dst,
    const float* __restrict__ gamma, const float* __restrict__ beta,
    const float* __restrict__ msinv)
{
    size_t idx = ((size_t)blockIdx.x * 256 + threadIdx.x) * 4;
    int c = (int)((idx / HWSZ) % C48);
    float mean = msinv[c * 2], inv = msinv[c * 2 + 1];
    float ga = gamma[c] * inv;
    float be = beta[c] - mean * ga;
    float4 v = ld4(src + idx);
    float4 r;
    r.x = fmaf(v.x, ga, be); r.y = fmaf(v.y, ga, be);
    r.z = fmaf(v.z, ga, be); r.w = fmaf(v.w, ga, be);
    st4(dst + idx, r);
}

// ---------------- tiled 3x3 conv with optional input-GN fold + fused epilogue/stats ----------------
// grid: (4 W-tiles of 64, 8 H-tiles of 16, B * CO/COPB); block 256 = 16x16
// If gPrev!=null, input is normalized during LDS staging: v = raw*ga(ci)+be(ci) (halo stays 0).

template<int CIN, int COPB, bool RELU, bool ADDH, typename TI, typename TO, typename TH>
__global__ __launch_bounds__(256) void conv3x3_kernel(
    const TI* __restrict__ in, const float* __restrict__ wgt,
    const TH* __restrict__ hadd, TO* __restrict__ out,
    double* __restrict__ dstats,
    const float* __restrict__ msPrev, const float* __restrict__ gPrev,
    const float* __restrict__ bPrev,
    int CO, int Cg, int CgIn)
{
    const int tid = threadIdx.x;
    const int tx = tid & 15;
    const int ty = tid >> 4;
    const int x0 = blockIdx.x * 64;
    const int y0 = blockIdx.y * 16;
    const int nb = CO / COPB;
    const int cob = (blockIdx.z % nb) * COPB;
    const int b   = blockIdx.z / nb;

    __shared__ __align__(16) float itile[18 * 72];
    __shared__ float wtile[COPB * CIN * 9];
    __shared__ double red[8];

    for (int i = tid; i < COPB * CIN * 9; i += 256) {
        int co = i / (CIN * 9);
        int rem = i - co * (CIN * 9);
        wtile[i] = wgt[(size_t)(cob + co) * (CIN * 9) + rem];
    }

    float acc[COPB][4];
    #pragma unroll
    for (int co = 0; co < COPB; co++)
        #pragma unroll
        for (int j = 0; j < 4; j++) acc[co][j] = 0.f;

    for (int ci = 0; ci < CIN; ci++) {
        __syncthreads();
        float ga = 1.f, be = 0.f;
        if (gPrev) {
            int pr = b * NGRP + ci / CgIn;
            float mean = msPrev[2 * pr], inv = msPrev[2 * pr + 1];
            ga = gPrev[ci] * inv;
            be = bPrev[ci] - mean * ga;
        }
        const TI* __restrict__ ip = in + (size_t)(b * CIN + ci) * HWSZ;
        for (int i = tid; i < 18 * 66; i += 256) {
            int r = i / 66, c = i - r * 66;
            int gy = y0 + r - 1, gx = x0 + c - 1;
            float v = 0.f;
            if ((unsigned)gy < (unsigned)HH && (unsigned)gx < (unsigned)WW)
                v = fmaf(ldS(ip + gy * WW + gx), ga, be);
            itile[r * 72 + c] = v;
        }
        __syncthreads();

        float a[3][6];
        #pragma unroll
        for (int rr = 0; rr < 3; rr++) {
            const float* p = &itile[(ty + rr) * 72 + 4 * tx];
            float4 v4 = *(const float4*)p;
            float2 v2 = *(const float2*)(p + 4);
            a[rr][0] = v4.x; a[rr][1] = v4.y; a[rr][2] = v4.z; a[rr][3] = v4.w;
            a[rr][4] = v2.x; a[rr][5] = v2.y;
        }
        #pragma unroll
        for (int co = 0; co < COPB; co++) {
            const float* wp = &wtile[(co * CIN + ci) * 9];
            #pragma unroll
            for (int rr = 0; rr < 3; rr++) {
                float w0 = wp[rr * 3 + 0], w1 = wp[rr * 3 + 1], w2 = wp[rr * 3 + 2];
                #pragma unroll
                for (int j = 0; j < 4; j++)
                    acc[co][j] = fmaf(a[rr][j], w0,
                                  fmaf(a[rr][j + 1], w1,
                                  fmaf(a[rr][j + 2], w2, acc[co][j])));
            }
        }
    }

    const bool valid = (x0 + 4 * tx) < WW;   // W%4==0: 4-group fully valid or fully out
    const int gy = y0 + ty;
    float vals[COPB][4];
    #pragma unroll
    for (int co = 0; co < COPB; co++)
        #pragma unroll
        for (int j = 0; j < 4; j++) {
            float v = acc[co][j];
            if (RELU) v = fmaxf(v, 0.f);
            vals[co][j] = v;
        }
    if (ADDH && valid) {
        #pragma unroll
        for (int co = 0; co < COPB; co++) {
            float4 hv = ld4(hadd + (size_t)((b * CO + cob + co) * HH + gy) * WW + x0 + 4 * tx);
            vals[co][0] += hv.x; vals[co][1] += hv.y; vals[co][2] += hv.z; vals[co][3] += hv.w;
        }
    }
    if (valid) {
        #pragma unroll
        for (int co = 0; co < COPB; co++) {
            float4 o;
            o.x = vals[co][0]; o.y = vals[co][1]; o.z = vals[co][2]; o.w = vals[co][3];
            st4(out + (size_t)((b * CO + cob + co) * HH + gy) * WW + x0 + 4 * tx, o);
        }
    }
    // fused GN stats in f64: pair = b*NGRP + co/Cg
    #pragma unroll
    for (int co = 0; co < COPB; co++) {
        double s = 0.0, q = 0.0;
        if (valid) {
            #pragma unroll
            for (int j = 0; j < 4; j++) {
                double v = (double)vals[co][j];
                s += v; q += v * v;
            }
        }
        int pair = b * NGRP + (cob + co) / Cg;
        stats_reduce_atomic_d(s, q, red, dstats + (size_t)pair * 2);
        __syncthreads();
    }
}

// ---------------- v = relu(z + gn2(u)) in place on u, fused gn3 stats ----------------

template<typename TU, typename TZ>
__global__ __launch_bounds__(256) void add_relu_gn2_kernel(
    TU* __restrict__ u, const TZ* __restrict__ z,
    const float* __restrict__ ms2, const float* __restrict__ g2,
    const float* __restrict__ b2, double* __restrict__ dstats3)
{
    __shared__ double red[8];
    size_t idx = ((size_t)blockIdx.x * 256 + threadIdx.x) * 4;
    int c = (int)((idx / HWSZ) % C48);
    int b = (int)(idx / ((size_t)C48 * HWSZ));
    int pair = b * NGRP + c / 6;
    float mean = ms2[pair * 2], inv = ms2[pair * 2 + 1];
    float ga = g2[c] * inv;
    float be = b2[c] - mean * ga;
    float4 uv = ld4(u + idx);
    float4 zv = ld4(z + idx);
    float4 v;
    v.x = fmaxf(fmaf(uv.x, ga, be) + zv.x, 0.f);
    v.y = fmaxf(fmaf(uv.y, ga, be) + zv.y, 0.f);
    v.z = fmaxf(fmaf(uv.z, ga, be) + zv.z, 0.f);
    v.w = fmaxf(fmaf(uv.w, ga, be) + zv.w, 0.f);
    st4(u + idx, v);
    double s = (double)v.x + v.y + v.z + v.w;
    double q = (double)v.x * v.x + (double)v.y * v.y + (double)v.z * v.z + (double)v.w * v.w;
    stats_reduce_atomic_d(s, q, red, dstats3 + (size_t)pair * 2);
}

// ---------------- gn3 apply: F = gn3(v); optionally G = F - z ----------------

template<typename TV, typename TZ, typename TO>
__global__ __launch_bounds__(256) void gn3_apply_kernel(
    const TV* __restrict__ v, const TZ* __restrict__ z,
    TO* __restrict__ F, TO* __restrict__ G,
    const float* __restrict__ ms3, const float* __restrict__ g3,
    const float* __restrict__ b3)
{
    size_t idx = ((size_t)blockIdx.x * 256 + threadIdx.x) * 4;
    int c = (int)((idx / HWSZ) % C48);
    int b = (int)(idx / ((size_t)C48 * HWSZ));
    int pair = b * NGRP + c / 6;
    float mean = ms3[pair * 2], inv = ms3[pair * 2 + 1];
    float ga = g3[c] * inv;
    float be = b3[c] - mean * ga;
    float4 vv = ld4(v + idx);
    float4 r;
    r.x = fmaf(vv.x, ga, be); r.y = fmaf(vv.y, ga, be);
    r.z = fmaf(vv.z, ga, be); r.w = fmaf(vv.w, ga, be);
    st4(F + idx, r);
    if (G) {
        float4 zv = ld4(z + idx);
        float4 g;
        g.x = r.x - zv.x; g.y = r.y - zv.y; g.z = r.z - zv.z; g.w = r.w - zv.w;
        st4(G + idx, g);
    }
}

// ---------------- Anderson machinery (f64 Gram + f64 solve) ----------------

__global__ void gram_zero_kernel(double* __restrict__ gram, int j, int n) {
    int t = threadIdx.x;
    if (t < 8 * n) {
        int b = t / n, i = t - (t / n) * n;
        gram[b * 25 + j * 5 + i] = 0.0;
        gram[b * 25 + i * 5 + j] = 0.0;
    }
}

// grid (75, 8): dot G_j . G_i for i<n (per batch), incremental Gram row/col update
template<typename T>
__global__ __launch_bounds__(256) void gram_update_kernel(
    const T* __restrict__ Gbase, double* __restrict__ gram, int j, int n)
{
    __shared__ double red[8];
    int b = blockIdx.y;
    const T* __restrict__ base = Gbase + (size_t)b * DPB;
    const T* __restrict__ gj = base + (size_t)j * SLOT;
    size_t f4s = (size_t)blockIdx.x * 4096 + threadIdx.x;
    double dot[5] = {0.0, 0.0, 0.0, 0.0, 0.0};
    for (int it = 0; it < 16; it++) {
        size_t p = (f4s + (size_t)it * 256) * 4;
        float4 gv = ld4(gj + p);
        #pragma unroll
        for (int i = 0; i < 5; i++) {
            if (i < n) {
                float4 gi = ld4(base + (size_t)i * SLOT + p);
                dot[i] += (double)gv.x * gi.x + (double)gv.y * gi.y
                        + (double)gv.z * gi.z + (double)gv.w * gi.w;
            }
        }
    }
    #pragma unroll
    for (int i = 0; i < 5; i++) {
        if (i >= n) continue;
        double s = dot[i];
        #pragma unroll
        for (int off = 32; off > 0; off >>= 1) s += __shfl_down(s, off);
        __syncthreads();
        if ((threadIdx.x & 63) == 0) red[threadIdx.x >> 6] = s;
        __syncthreads();
        if (threadIdx.x == 0) {
            double S = red[0] + red[1] + red[2] + red[3];
            atomicAdd(&gram[b * 25 + j * 5 + i], S);
            if (i != j) atomicAdd(&gram[b * 25 + i * 5 + j], S);
        }
    }
}

// per-batch (n+1)x(n+1) bordered solve in f64, Gauss-Jordan w/ partial pivoting
__global__ void solve_kernel(const double* __restrict__ gram, float* __restrict__ alpha, int n) {
    int b = threadIdx.x;
    if (b >= BB) return;
    const int m = n + 1;
    double A[6][7];
    for (int i = 0; i < m; i++)
        for (int jj = 0; jj <= m; jj++) A[i][jj] = 0.0;
    for (int i = 1; i < m; i++) { A[0][i] = 1.0; A[i][0] = 1.0; }
    for (int i = 1; i < m; i++)
        for (int jj = 1; jj < m; jj++)
            A[i][jj] = gram[b * 25 + (i - 1) * 5 + (jj - 1)] + ((i == jj) ? LAMV : 0.0);
    A[0][m] = 1.0;  // rhs = e0
    for (int col = 0; col < m; col++) {
        int piv = col; double best = fabs(A[col][col]);
        for (int rr = col + 1; rr < m; rr++) {
            double tv = fabs(A[rr][col]);
            if (tv > best) { best = tv; piv = rr; }
        }
        if (piv != col)
            for (int cc = col; cc <= m; cc++) {
                double tmp = A[col][cc]; A[col][cc] = A[piv][cc]; A[piv][cc] = tmp;
            }
        double invp = 1.0 / A[col][col];
        for (int cc = col; cc <= m; cc++) A[col][cc] *= invp;
        for (int rr = 0; rr < m; rr++) {
            if (rr == col) continue;
            double f = A[rr][col];
            if (f != 0.0)
                for (int cc = col; cc <= m; cc++) A[rr][cc] = fma(-f, A[col][cc], A[rr][cc]);
        }
    }
    for (int i = 0; i < n; i++) alpha[b * 5 + i] = (float)A[i + 1][m];
}

// xk = sum_i alpha[b][i] * F_i   (beta == 1.0)
template<typename T>
__global__ __launch_bounds__(256) void xk_kernel(
    const T* __restrict__ Fb, const float* __restrict__ alpha,
    T* __restrict__ zcur, int n)
{
    size_t idx = ((size_t)blockIdx.x * 256 + threadIdx.x) * 4;
    int b = (int)(idx / DPB);
    float4 s; s.x = s.y = s.z = s.w = 0.f;
    #pragma unroll
    for (int j = 0; j < 5; j++) {
        if (j < n) {
            float al = alpha[b * 5 + j];
            float4 f = ld4(Fb + (size_t)j * SLOT + idx);
            s.x = fmaf(f.x, al, s.x); s.y = fmaf(f.y, al, s.y);
            s.z = fmaf(f.z, al, s.z); s.w = fmaf(f.w, al, s.w);
        }
    }
    st4(zcur + idx, s);
}

// ---------------- final linear (reads fp32 scratch) ----------------

__global__ __launch_bounds__(256) void fc_kernel(
    const float* __restrict__ z, const float* __restrict__ fw,
    const float* __restrict__ fb, float* __restrict__ out)
{
    int idx = blockIdx.x * 256 + threadIdx.x;  // 491520
    int o = idx % 10;
    int row = idx / 10;
    const float* zr = z + (size_t)row * WW;
    const float* wr = fw + o * WW;
    float acc = fb[o];
    #pragma unroll 5
    for (int k = 0; k < 50; k++) {
        float4 zv = *(const float4*)(zr + 4 * k);
        float4 wv = *(const float4*)(wr + 4 * k);
        acc = fmaf(zv.x, wv.x, acc); acc = fmaf(zv.y, wv.y, acc);
        acc = fmaf(zv.z, wv.z, acc); acc = fmaf(zv.w, wv.w, acc);
    }
    out[idx] = acc;
}

// ---------------- host ----------------

static inline int imin(int a, int b) { return a < b ? a : b; }

template<typename T>
static void run_pipeline(void* const* d_in, float* out, void* d_ws, hipStream_t stream)
{
    const float* x   = (const float*)d_in[0];
    const float* w0  = (const float*)d_in[1];
    const float* b0  = (const float*)d_in[2];
    const float* bng = (const float*)d_in[3];
    const float* bnb = (const float*)d_in[4];
    const float* w1  = (const float*)d_in[5];
    const float* w2  = (const float*)d_in[6];
    const float* g1  = (const float*)d_in[7];
    const float* be1 = (const float*)d_in[8];
    const float* g2  = (const float*)d_in[9];
    const float* be2 = (const float*)d_in[10];
    const float* g3  = (const float*)d_in[11];
    const float* be3 = (const float*)d_in[12];
    const float* fcw = (const float*)d_in[13];
    const float* fcb = (const float*)d_in[14];

    T* h    = (T*)d_ws;                    // SLOT
    T* zcur = h + (size_t)SLOT;            // SLOT
    T* y64  = zcur + (size_t)SLOT;         // Y64SZ
    T* Fb   = y64 + (size_t)Y64SZ;         // 5*SLOT
    T* Gb   = Fb + 5 * (size_t)SLOT;       // 5*SLOT
    // stats region after the big buffers
    char* statbase = (char*)d_ws + BIGELEMS * sizeof(T);
    double* dstats = (double*)statbase;    // 9696 doubles: BN 96 + 25 calls * 384
    double* gram   = dstats + 9696;        // 200 doubles
    float*  msinv  = (float*)(gram + 200); // 9696 floats
    float*  alpha  = msinv + 9696;         // 40 floats
    // fp32 scratch overlaying the (dead at use-time) G region: conv0 raw + final resnet output
    float* scratch = (float*)Gb;           // SLOT fp32 fits in 5*SLOT*sizeof(T) for both tiers

    const dim3 blk(256);
    const int SLOT_QBLK = SLOT / 4 / 256;                          // 9600 (4 elems/thread)
    const int CHUNKS16  = (int)((size_t)SLOT * sizeof(T) / 16 / 256);  // 16B-chunk blocks per slot

    // zero f64 stats + gram (ws is re-poisoned before every launch)
    zero_kernel<<<(19792 + 255) / 256, blk, 0, stream>>>((float*)dstats, 19792);
    // z0 = 0
    fill16_kernel<<<CHUNKS16, blk, 0, stream>>>((float4*)zcur);

    // h = BN(conv0(x) + b0)
    conv0_kernel<<<SLOT / 256, blk, 0, stream>>>(x, w0, b0, scratch, dstats);
    finalize_kernel<<<1, 64, 0, stream>>>(dstats, msinv, C48, 1.0 / 204800.0);
    bn_apply_kernel<T><<<SLOT_QBLK, blk, 0, stream>>>(scratch, h, bng, bnb, msinv);

    int call = 0;
    // resnet_f: if finalOut==null, writes F into Fdst (T) and G into Gdst (T);
    // else writes fp32 result into finalOut.
    auto resnet = [&](const T* zin, T* Fdst, T* Gdst, float* finalOut) {
        double* ds = dstats + 96 + 384 * call;
        float*  ms = msinv + 96 + 384 * call;
        call++;
        dim3 cg1(4, 8, BB * (C64 / 8));
        conv3x3_kernel<48, 8, true, false, T, T, T><<<cg1, blk, 0, stream>>>(
            zin, w1, (const T*)nullptr, y64, ds, nullptr, nullptr, nullptr, C64, 8, 0);
        finalize_kernel<<<1, 64, 0, stream>>>(ds, ms, 64, 1.0 / 204800.0);
        dim3 cg2(4, 8, BB * (C48 / 8));
        if (!finalOut) {
            conv3x3_kernel<64, 8, false, true, T, T, T><<<cg2, blk, 0, stream>>>(
                y64, w2, h, Fdst, ds + 128, ms, g1, be1, C48, 6, 8);
            finalize_kernel<<<1, 64, 0, stream>>>(ds + 128, ms + 128, 64, 1.0 / 153600.0);
            add_relu_gn2_kernel<T, T><<<SLOT_QBLK, blk, 0, stream>>>(
                Fdst, zin, ms + 128, g2, be2, ds + 256);
            finalize_kernel<<<1, 64, 0, stream>>>(ds + 256, ms + 256, 64, 1.0 / 153600.0);
            gn3_apply_kernel<T, T, T><<<SLOT_QBLK, blk, 0, stream>>>(
                Fdst, zin, Fdst, Gdst, ms + 256, g3, be3);
        } else {
            conv3x3_kernel<64, 8, false, true, T, float, T><<<cg2, blk, 0, stream>>>(
                y64, w2, h, finalOut, ds + 128, ms, g1, be1, C48, 6, 8);
            finalize_kernel<<<1, 64, 0, stream>>>(ds + 128, ms + 128, 64, 1.0 / 153600.0);
            add_relu_gn2_kernel<float, T><<<SLOT_QBLK, blk, 0, stream>>>(
                finalOut, zin, ms + 128, g2, be2, ds + 256);
            finalize_kernel<<<1, 64, 0, stream>>>(ds + 256, ms + 256, 64, 1.0 / 153600.0);
            gn3_apply_kernel<float, T, float><<<SLOT_QBLK, blk, 0, stream>>>(
                finalOut, (const T*)nullptr, finalOut, (float*)nullptr, ms + 256, g3, be3);
        }
    };

    // slot 0: X=0, F0=f(0), G0=F0-0
    resnet(zcur, Fb, Gb, nullptr);
    gram_zero_kernel<<<1, 64, 0, stream>>>(gram, 0, 1);
    gram_update_kernel<T><<<dim3(75, 8), blk, 0, stream>>>(Gb, gram, 0, 1);

    // slot 1: X=F0, F1=f(F0), G1=F1-F0
    copy16_kernel<<<CHUNKS16, blk, 0, stream>>>((float4*)zcur, (const float4*)Fb);
    resnet(zcur, Fb + (size_t)SLOT, Gb + (size_t)SLOT, nullptr);
    gram_zero_kernel<<<1, 64, 0, stream>>>(gram, 1, 2);
    gram_update_kernel<T><<<dim3(75, 8), blk, 0, stream>>>(Gb, gram, 1, 2);

    for (int k = 2; k <= 24; k++) {
        int n = imin(k, 5);
        int j = k % 5;
        solve_kernel<<<1, 64, 0, stream>>>(gram, alpha, n);
        xk_kernel<T><<<SLOT_QBLK, blk, 0, stream>>>(Fb, alpha, zcur, n);
        if (k < 24) {  // reference computes Fv at k=24 but never uses it
            resnet(zcur, Fb + (size_t)j * SLOT, Gb + (size_t)j * SLOT, nullptr);
            int nf = imin(k + 1, 5);
            gram_zero_kernel<<<1, 64, 0, stream>>>(gram, j, nf);
            gram_update_kernel<T><<<dim3(75, 8), blk, 0, stream>>>(Gb, gram, j, nf);
        }
    }

    // z_star = zcur (= x_24); one extra f application -> fp32 scratch
    resnet(zcur, nullptr, nullptr, scratch);

    // final linear: [8,48,128,200] x [10,200]^T -> [8,48,128,10]
    fc_kernel<<<(BB * C48 * HH * 10) / 256, blk, 0, stream>>>(scratch, fcw, fcb, (float*)out);
}

extern "C" void kernel_launch(void* const* d_in, const int* in_sizes, int n_in,
                              void* d_out, int out_size, void* d_ws, size_t ws_size,
                              hipStream_t stream)
{
    const size_t STATB  = 9696 * 8 + 200 * 8 + 9696 * 4 + 40 * 4;  // 118112 B
    const size_t need32 = BIGELEMS * 4 + STATB;  // ~524.4 MB: all-fp32 tier
    const size_t need16 = BIGELEMS * 2 + STATB;  // ~262.3 MB: bf16-storage tier

    if (ws_size >= need32) {
        run_pipeline<float>(d_in, (float*)d_out, d_ws, stream);
    } else if (ws_size >= need16) {
        run_pipeline<bf16_t>(d_in, (float*)d_out, d_ws, stream);
    }
    // else: workspace too small for any layout — nothing we can safely do
}

// Round 4
// 22052.167 us; speedup vs baseline: 1.0889x; 1.0889x over previous
//
#include <hip/hip_runtime.h>

#define BB   8
#define HH   128
#define WW   200
#define HWSZ 25600            // HH*WW
#define C48  48
#define C64  64
#define NGRP 8
#define EPSV 1e-5f
#define LAMV 1e-4
#define SLOT 9830400          // BB*C48*HWSZ (one z/F/G slot, elements)
#define DPB  1228800          // C48*HWSZ (per-batch flat dim)
#define Y64SZ 13107200        // BB*C64*HWSZ
#define BIGELEMS 131072000ull // 12*SLOT + Y64SZ

// ---------------- bf16 storage helpers (compute always fp32) ----------------

typedef unsigned short bf16_t;

__device__ inline float b2f(bf16_t b) { return __uint_as_float(((unsigned)b) << 16); }
__device__ inline bf16_t f2b(float f) {           // round-to-nearest-even
    unsigned u = __float_as_uint(f);
    unsigned r = u + 0x7fffu + ((u >> 16) & 1u);
    return (bf16_t)(r >> 16);
}
__device__ inline float ldS(const float* p) { return *p; }
__device__ inline float ldS(const bf16_t* p) { return b2f(*p); }
__device__ inline float4 ld4(const float* p) { return *(const float4*)p; }
__device__ inline float4 ld4(const bf16_t* p) {
    ushort4 u = *(const ushort4*)p;
    return make_float4(b2f(u.x), b2f(u.y), b2f(u.z), b2f(u.w));
}
__device__ inline void st4(float* p, float4 v) { *(float4*)p = v; }
__device__ inline void st4(bf16_t* p, float4 v) {
    ushort4 u; u.x = f2b(v.x); u.y = f2b(v.y); u.z = f2b(v.z); u.w = f2b(v.w);
    *(ushort4*)p = u;
}

// (mean, invstd) from f64 sums, computed at use site
__device__ inline void ms_from(const double* __restrict__ ds, int pair, double invcnt,
                               float& mean, float& inv) {
    double s = ds[2 * pair], q = ds[2 * pair + 1];
    double m = s * invcnt;
    double v = q * invcnt - m * m;
    mean = (float)m;
    inv = (float)(1.0 / sqrt(v + (double)EPSV));
}

// ---------------- small utility kernels ----------------

__global__ void zero_kernel(float* __restrict__ p, int n) {
    int i = blockIdx.x * 256 + threadIdx.x;
    if (i < n) p[i] = 0.f;
}

__global__ void fill16_kernel(float4* __restrict__ p) {   // grid*256 16B chunks
    float4 z; z.x = z.y = z.z = z.w = 0.f;
    p[(size_t)blockIdx.x * 256 + threadIdx.x] = z;
}

__global__ void copy16_kernel(float4* __restrict__ dst, const float4* __restrict__ src) {
    size_t i = (size_t)blockIdx.x * 256 + threadIdx.x;
    dst[i] = src[i];
}

// f64 block reduction + one atomic per block (sum, sumsq)
__device__ inline void stats_reduce_atomic_d(double s, double q, double* red, double* dst) {
    #pragma unroll
    for (int off = 32; off > 0; off >>= 1) {
        s += __shfl_down(s, off);
        q += __shfl_down(q, off);
    }
    __syncthreads();
    if ((threadIdx.x & 63) == 0) { red[threadIdx.x >> 6] = s; red[4 + (threadIdx.x >> 6)] = q; }
    __syncthreads();
    if (threadIdx.x == 0) {
        atomicAdd(dst + 0, red[0] + red[1] + red[2] + red[3]);
        atomicAdd(dst + 1, red[4] + red[5] + red[6] + red[7]);
    }
}

// ---------------- conv0 (1->48) + BN stats (always fp32 in/out) ----------------

__global__ __launch_bounds__(256) void conv0_kernel(
    const float* __restrict__ x, const float* __restrict__ w,
    const float* __restrict__ bias, float* __restrict__ out,
    double* __restrict__ dstats)
{
    __shared__ double red[8];
    int idx = blockIdx.x * 256 + threadIdx.x;     // B*48*HW, exact multiple of 256
    int xw = idx % WW;
    int t  = idx / WW;
    int yh = t % HH; t /= HH;
    int c  = t % C48;
    int b  = t / C48;
    const float* __restrict__ xp = x + (size_t)b * HWSZ;
    const float* __restrict__ wc = w + c * 9;
    float acc = bias[c];
    #pragma unroll
    for (int dy = 0; dy < 3; dy++) {
        int gy = yh + dy - 1;
        if ((unsigned)gy >= (unsigned)HH) continue;
        #pragma unroll
        for (int dx = 0; dx < 3; dx++) {
            int gx = xw + dx - 1;
            if ((unsigned)gx >= (unsigned)WW) continue;
            acc = fmaf(xp[gy * WW + gx], wc[dy * 3 + dx], acc);
        }
    }
    out[idx] = acc;
    double dv = (double)acc;
    stats_reduce_atomic_d(dv, dv * dv, red, dstats + (size_t)c * 2);  // pair = channel
}

// BN apply: raw fp32 -> h (T storage); mean/inv computed inline from f64 sums
template<typename TO>
__global__ __launch_bounds__(256) void bn_apply_kernel(
    const float* __restrict__ src, TO* __restrict__ dst,
    const float* __restrict__ gamma, const float* __restrict__ beta,
    const double* __restrict__ ds)
{
    size_t idx = ((size_t)blockIdx.x * 256 + threadIdx.x) * 4;
    int c = (int)((idx / HWSZ) % C48);
    float mean, inv;
    ms_from(ds, c, 1.0 / 204800.0, mean, inv);
    float ga = gamma[c] * inv;
    float be = beta[c] - mean * ga;
    float4 v = ld4(src + idx);
    float4 r;
    r.x = fmaf(v.x, ga, be); r.y = fmaf(v.y, ga, be);
    r.z = fmaf(v.z, ga, be); r.w = fmaf(v.w, ga, be);
    st4(dst + idx, r);
}

// ---------------- tiled 3x3 conv, weights via wave-uniform scalar loads ----------------
// grid: (4 W-tiles of 64, 8 H-tiles of 16, B * CO/COPB); block 256 = 16x16
// If FOLDGN, input is normalized during LDS staging via a per-channel ga/be LDS table
// (halo stays 0 = post-norm zero padding, matching reference SAME padding).

template<int CIN, int COPB, bool RELU, bool ADDH, bool FOLDGN, typename TI, typename TO, typename TH>
__global__ __launch_bounds__(256) void conv3x3_kernel(
    const TI* __restrict__ in, const float* __restrict__ wgt,
    const TH* __restrict__ hadd, TO* __restrict__ out,
    double* __restrict__ dstats,
    const double* __restrict__ dsPrev, double invPrev,
    const float* __restrict__ gPrev, const float* __restrict__ bPrev,
    int CO, int Cg, int CgIn)
{
    const int tid = threadIdx.x;
    const int tx = tid & 15;
    const int ty = tid >> 4;
    const int x0 = blockIdx.x * 64;
    const int y0 = blockIdx.y * 16;
    const int nb = CO / COPB;
    const int cob = (blockIdx.z % nb) * COPB;
    const int b   = blockIdx.z / nb;

    __shared__ __align__(16) float itile[18 * 72];
    __shared__ float gtab[FOLDGN ? 2 * CIN : 2];
    __shared__ double red[8];

    if (FOLDGN) {
        if (tid < CIN) {
            int pr = b * NGRP + tid / CgIn;
            float mean, inv;
            ms_from(dsPrev, pr, invPrev, mean, inv);
            float ga = gPrev[tid] * inv;
            gtab[2 * tid]     = ga;
            gtab[2 * tid + 1] = bPrev[tid] - mean * ga;
        }
        // first loop-top barrier publishes gtab
    }

    float acc[COPB][4];
    #pragma unroll
    for (int co = 0; co < COPB; co++)
        #pragma unroll
        for (int j = 0; j < 4; j++) acc[co][j] = 0.f;

    const float* __restrict__ wb = wgt + (size_t)cob * (CIN * 9);

    for (int ci = 0; ci < CIN; ci++) {
        __syncthreads();
        float ga = 1.f, be = 0.f;
        if (FOLDGN) { ga = gtab[2 * ci]; be = gtab[2 * ci + 1]; }
        const TI* __restrict__ ip = in + (size_t)(b * CIN + ci) * HWSZ;
        for (int i = tid; i < 18 * 66; i += 256) {
            int r = i / 66, c = i - r * 66;
            int gy = y0 + r - 1, gx = x0 + c - 1;
            float v = 0.f;
            if ((unsigned)gy < (unsigned)HH && (unsigned)gx < (unsigned)WW)
                v = fmaf(ldS(ip + gy * WW + gx), ga, be);
            itile[r * 72 + c] = v;
        }
        __syncthreads();

        float a[3][6];
        #pragma unroll
        for (int rr = 0; rr < 3; rr++) {
            const float* p = &itile[(ty + rr) * 72 + 4 * tx];
            float4 v4 = *(const float4*)p;
            float2 v2 = *(const float2*)(p + 4);
            a[rr][0] = v4.x; a[rr][1] = v4.y; a[rr][2] = v4.z; a[rr][3] = v4.w;
            a[rr][4] = v2.x; a[rr][5] = v2.y;
        }
        #pragma unroll
        for (int co = 0; co < COPB; co++) {
            // wave-uniform indices -> scalar loads (SGPR weights, no LDS traffic)
            const float* __restrict__ wp = wb + ((size_t)co * CIN + ci) * 9;
            #pragma unroll
            for (int rr = 0; rr < 3; rr++) {
                float w0 = wp[rr * 3 + 0], w1 = wp[rr * 3 + 1], w2 = wp[rr * 3 + 2];
                #pragma unroll
                for (int j = 0; j < 4; j++)
                    acc[co][j] = fmaf(a[rr][j], w0,
                                  fmaf(a[rr][j + 1], w1,
                                  fmaf(a[rr][j + 2], w2, acc[co][j])));
            }
        }
    }

    const bool valid = (x0 + 4 * tx) < WW;   // W%4==0: 4-group fully valid or fully out
    const int gy = y0 + ty;
    float vals[COPB][4];
    #pragma unroll
    for (int co = 0; co < COPB; co++)
        #pragma unroll
        for (int j = 0; j < 4; j++) {
            float v = acc[co][j];
            if (RELU) v = fmaxf(v, 0.f);
            vals[co][j] = v;
        }
    if (ADDH && valid) {
        #pragma unroll
        for (int co = 0; co < COPB; co++) {
            float4 hv = ld4(hadd + (size_t)((b * CO + cob + co) * HH + gy) * WW + x0 + 4 * tx);
            vals[co][0] += hv.x; vals[co][1] += hv.y; vals[co][2] += hv.z; vals[co][3] += hv.w;
        }
    }
    if (valid) {
        #pragma unroll
        for (int co = 0; co < COPB; co++) {
            float4 o;
            o.x = vals[co][0]; o.y = vals[co][1]; o.z = vals[co][2]; o.w = vals[co][3];
            st4(out + (size_t)((b * CO + cob + co) * HH + gy) * WW + x0 + 4 * tx, o);
        }
    }
    // fused GN stats: accumulate per-group in registers, 1-2 atomics per block
    const int gfirst = cob / Cg, glast = (cob + COPB - 1) / Cg;
    for (int g = gfirst; g <= glast; g++) {
        double s = 0.0, q = 0.0;
        if (valid) {
            #pragma unroll
            for (int co = 0; co < COPB; co++) {
                if ((cob + co) / Cg == g) {
                    #pragma unroll
                    for (int j = 0; j < 4; j++) {
                        double v = (double)vals[co][j];
                        s += v; q += v * v;
                    }
                }
            }
        }
        stats_reduce_atomic_d(s, q, red, dstats + (size_t)(b * NGRP + g) * 2);
    }
}

// ---------------- v = relu(z + gn2(u)) in place on u, fused gn3 stats ----------------

template<typename TU, typename TZ>
__global__ __launch_bounds__(256) void add_relu_gn2_kernel(
    TU* __restrict__ u, const TZ* __restrict__ z,
    const double* __restrict__ ds2, const float* __restrict__ g2,
    const float* __restrict__ b2, double* __restrict__ dstats3)
{
    __shared__ double red[8];
    size_t idx = ((size_t)blockIdx.x * 256 + threadIdx.x) * 4;
    int c = (int)((idx / HWSZ) % C48);
    int b = (int)(idx / ((size_t)C48 * HWSZ));
    int pair = b * NGRP + c / 6;
    float mean, inv;
    ms_from(ds2, pair, 1.0 / 153600.0, mean, inv);
    float ga = g2[c] * inv;
    float be = b2[c] - mean * ga;
    float4 uv = ld4(u + idx);
    float4 zv = ld4(z + idx);
    float4 v;
    v.x = fmaxf(fmaf(uv.x, ga, be) + zv.x, 0.f);
    v.y = fmaxf(fmaf(uv.y, ga, be) + zv.y, 0.f);
    v.z = fmaxf(fmaf(uv.z, ga, be) + zv.z, 0.f);
    v.w = fmaxf(fmaf(uv.w, ga, be) + zv.w, 0.f);
    st4(u + idx, v);
    double s = (double)v.x + v.y + v.z + v.w;
    double q = (double)v.x * v.x + (double)v.y * v.y + (double)v.z * v.z + (double)v.w * v.w;
    stats_reduce_atomic_d(s, q, red, dstats3 + (size_t)pair * 2);
}

// ---------------- gn3 apply: F = gn3(v); optionally G = F - z ----------------

template<typename TV, typename TZ, typename TO>
__global__ __launch_bounds__(256) void gn3_apply_kernel(
    const TV* __restrict__ v, const TZ* __restrict__ z,
    TO* __restrict__ F, TO* __restrict__ G,
    const double* __restrict__ ds3, const float* __restrict__ g3,
    const float* __restrict__ b3)
{
    size_t idx = ((size_t)blockIdx.x * 256 + threadIdx.x) * 4;
    int c = (int)((idx / HWSZ) % C48);
    int b = (int)(idx / ((size_t)C48 * HWSZ));
    int pair = b * NGRP + c / 6;
    float mean, inv;
    ms_from(ds3, pair, 1.0 / 153600.0, mean, inv);
    float ga = g3[c] * inv;
    float be = b3[c] - mean * ga;
    float4 vv = ld4(v + idx);
    float4 r;
    r.x = fmaf(vv.x, ga, be); r.y = fmaf(vv.y, ga, be);
    r.z = fmaf(vv.z, ga, be); r.w = fmaf(vv.w, ga, be);
    st4(F + idx, r);
    if (G) {
        float4 zv = ld4(z + idx);
        float4 g;
        g.x = r.x - zv.x; g.y = r.y - zv.y; g.z = r.z - zv.z; g.w = r.w - zv.w;
        st4(G + idx, g);
    }
}

// ---------------- Anderson machinery (f64 Gram + f64 solve) ----------------

__global__ void gram_zero_kernel(double* __restrict__ gram, int j, int n) {
    int t = threadIdx.x;
    if (t < 8 * n) {
        int b = t / n, i = t - (t / n) * n;
        gram[b * 25 + j * 5 + i] = 0.0;
        gram[b * 25 + i * 5 + j] = 0.0;
    }
}

// grid (75, 8): dot G_j . G_i for i<n (per batch), incremental Gram row/col update
template<typename T>
__global__ __launch_bounds__(256) void gram_update_kernel(
    const T* __restrict__ Gbase, double* __restrict__ gram, int j, int n)
{
    __shared__ double red[8];
    int b = blockIdx.y;
    const T* __restrict__ base = Gbase + (size_t)b * DPB;
    const T* __restrict__ gj = base + (size_t)j * SLOT;
    size_t f4s = (size_t)blockIdx.x * 4096 + threadIdx.x;
    double dot[5] = {0.0, 0.0, 0.0, 0.0, 0.0};
    for (int it = 0; it < 16; it++) {
        size_t p = (f4s + (size_t)it * 256) * 4;
        float4 gv = ld4(gj + p);
        #pragma unroll
        for (int i = 0; i < 5; i++) {
            if (i < n) {
                float4 gi = ld4(base + (size_t)i * SLOT + p);
                dot[i] += (double)gv.x * gi.x + (double)gv.y * gi.y
                        + (double)gv.z * gi.z + (double)gv.w * gi.w;
            }
        }
    }
    #pragma unroll
    for (int i = 0; i < 5; i++) {
        if (i >= n) continue;
        double s = dot[i];
        #pragma unroll
        for (int off = 32; off > 0; off >>= 1) s += __shfl_down(s, off);
        __syncthreads();
        if ((threadIdx.x & 63) == 0) red[threadIdx.x >> 6] = s;
        __syncthreads();
        if (threadIdx.x == 0) {
            double S = red[0] + red[1] + red[2] + red[3];
            atomicAdd(&gram[b * 25 + j * 5 + i], S);
            if (i != j) atomicAdd(&gram[b * 25 + i * 5 + j], S);
        }
    }
}

// per-batch (n+1)x(n+1) bordered solve in f64, Gauss-Jordan w/ partial pivoting
__global__ void solve_kernel(const double* __restrict__ gram, float* __restrict__ alpha, int n) {
    int b = threadIdx.x;
    if (b >= BB) return;
    const int m = n + 1;
    double A[6][7];
    for (int i = 0; i < m; i++)
        for (int jj = 0; jj <= m; jj++) A[i][jj] = 0.0;
    for (int i = 1; i < m; i++) { A[0][i] = 1.0; A[i][0] = 1.0; }
    for (int i = 1; i < m; i++)
        for (int jj = 1; jj < m; jj++)
            A[i][jj] = gram[b * 25 + (i - 1) * 5 + (jj - 1)] + ((i == jj) ? LAMV : 0.0);
    A[0][m] = 1.0;  // rhs = e0
    for (int col = 0; col < m; col++) {
        int piv = col; double best = fabs(A[col][col]);
        for (int rr = col + 1; rr < m; rr++) {
            double tv = fabs(A[rr][col]);
            if (tv > best) { best = tv; piv = rr; }
        }
        if (piv != col)
            for (int cc = col; cc <= m; cc++) {
                double tmp = A[col][cc]; A[col][cc] = A[piv][cc]; A[piv][cc] = tmp;
            }
        double invp = 1.0 / A[col][col];
        for (int cc = col; cc <= m; cc++) A[col][cc] *= invp;
        for (int rr = 0; rr < m; rr++) {
            if (rr == col) continue;
            double f = A[rr][col];
            if (f != 0.0)
                for (int cc = col; cc <= m; cc++) A[rr][cc] = fma(-f, A[col][cc], A[rr][cc]);
        }
    }
    for (int i = 0; i < n; i++) alpha[b * 5 + i] = (float)A[i + 1][m];
}

// xk = sum_i alpha[b][i] * F_i  (beta == 1.0); block 0 also zeroes gram row/col jz
template<typename T>
__global__ __launch_bounds__(256) void xk_kernel(
    const T* __restrict__ Fb, const float* __restrict__ alpha,
    T* __restrict__ zcur, int n, double* __restrict__ gram, int jz, int nf)
{
    if (blockIdx.x == 0 && threadIdx.x < 8 * nf) {
        int b = threadIdx.x / nf, i = threadIdx.x % nf;
        gram[b * 25 + jz * 5 + i] = 0.0;
        gram[b * 25 + i * 5 + jz] = 0.0;
    }
    size_t idx = ((size_t)blockIdx.x * 256 + threadIdx.x) * 4;
    int b = (int)(idx / DPB);
    float4 s; s.x = s.y = s.z = s.w = 0.f;
    #pragma unroll
    for (int j = 0; j < 5; j++) {
        if (j < n) {
            float al = alpha[b * 5 + j];
            float4 f = ld4(Fb + (size_t)j * SLOT + idx);
            s.x = fmaf(f.x, al, s.x); s.y = fmaf(f.y, al, s.y);
            s.z = fmaf(f.z, al, s.z); s.w = fmaf(f.w, al, s.w);
        }
    }
    st4(zcur + idx, s);
}

// ---------------- final linear (reads fp32 scratch) ----------------

__global__ __launch_bounds__(256) void fc_kernel(
    const float* __restrict__ z, const float* __restrict__ fw,
    const float* __restrict__ fb, float* __restrict__ out)
{
    int idx = blockIdx.x * 256 + threadIdx.x;  // 491520
    int o = idx % 10;
    int row = idx / 10;
    const float* zr = z + (size_t)row * WW;
    const float* wr = fw + o * WW;
    float acc = fb[o];
    #pragma unroll 5
    for (int k = 0; k < 50; k++) {
        float4 zv = *(const float4*)(zr + 4 * k);
        float4 wv = *(const float4*)(wr + 4 * k);
        acc = fmaf(zv.x, wv.x, acc); acc = fmaf(zv.y, wv.y, acc);
        acc = fmaf(zv.z, wv.z, acc); acc = fmaf(zv.w, wv.w, acc);
    }
    out[idx] = acc;
}

// ---------------- host ----------------

static inline int imin(int a, int b) { return a < b ? a : b; }

template<typename T>
static void run_pipeline(void* const* d_in, float* out, void* d_ws, hipStream_t stream)
{
    const float* x   = (const float*)d_in[0];
    const float* w0  = (const float*)d_in[1];
    const float* b0  = (const float*)d_in[2];
    const float* bng = (const float*)d_in[3];
    const float* bnb = (const float*)d_in[4];
    const float* w1  = (const float*)d_in[5];
    const float* w2  = (const float*)d_in[6];
    const float* g1  = (const float*)d_in[7];
    const float* be1 = (const float*)d_in[8];
    const float* g2  = (const float*)d_in[9];
    const float* be2 = (const float*)d_in[10];
    const float* g3  = (const float*)d_in[11];
    const float* be3 = (const float*)d_in[12];
    const float* fcw = (const float*)d_in[13];
    const float* fcb = (const float*)d_in[14];

    T* h    = (T*)d_ws;                    // SLOT
    T* zcur = h + (size_t)SLOT;            // SLOT
    T* y64  = zcur + (size_t)SLOT;         // Y64SZ
    T* Fb   = y64 + (size_t)Y64SZ;         // 5*SLOT
    T* Gb   = Fb + 5 * (size_t)SLOT;       // 5*SLOT
    // stats region after the big buffers
    char* statbase = (char*)d_ws + BIGELEMS * sizeof(T);
    double* dstats = (double*)statbase;    // 9696 doubles: BN 96 + 25 calls * 384
    double* gram   = dstats + 9696;        // 200 doubles
    float*  alpha  = (float*)(gram + 200); // 40 floats
    // fp32 scratch overlaying the (dead at use-time) G region: conv0 raw + final resnet output
    float* scratch = (float*)Gb;           // SLOT fp32 fits in 5*SLOT*sizeof(T) for both tiers

    const dim3 blk(256);
    const int SLOT_QBLK = SLOT / 4 / 256;                          // 9600 (4 elems/thread)
    const int CHUNKS16  = (int)((size_t)SLOT * sizeof(T) / 16 / 256);  // 16B-chunk blocks per slot

    // zero f64 stats + gram (ws is re-poisoned before every launch)
    zero_kernel<<<(19792 + 255) / 256, blk, 0, stream>>>((float*)dstats, 19792);
    // z0 = 0
    fill16_kernel<<<CHUNKS16, blk, 0, stream>>>((float4*)zcur);

    // h = BN(conv0(x) + b0)
    conv0_kernel<<<SLOT / 256, blk, 0, stream>>>(x, w0, b0, scratch, dstats);
    bn_apply_kernel<T><<<SLOT_QBLK, blk, 0, stream>>>(scratch, h, bng, bnb, dstats);

    int call = 0;
    // resnet_f: if finalOut==null, writes F into Fdst (T) and G into Gdst (T);
    // else writes fp32 result into finalOut.
    auto resnet = [&](const T* zin, T* Fdst, T* Gdst, float* finalOut) {
        double* ds = dstats + 96 + 384 * call;
        call++;
        dim3 cg1(4, 8, BB * (C64 / 8));
        conv3x3_kernel<48, 8, true, false, false, T, T, T><<<cg1, blk, 0, stream>>>(
            zin, w1, (const T*)nullptr, y64, ds,
            nullptr, 0.0, nullptr, nullptr, C64, 8, 0);
        dim3 cg2(4, 8, BB * (C48 / 8));
        if (!finalOut) {
            conv3x3_kernel<64, 8, false, true, true, T, T, T><<<cg2, blk, 0, stream>>>(
                y64, w2, h, Fdst, ds + 128,
                ds, 1.0 / 204800.0, g1, be1, C48, 6, 8);
            add_relu_gn2_kernel<T, T><<<SLOT_QBLK, blk, 0, stream>>>(
                Fdst, zin, ds + 128, g2, be2, ds + 256);
            gn3_apply_kernel<T, T, T><<<SLOT_QBLK, blk, 0, stream>>>(
                Fdst, zin, Fdst, Gdst, ds + 256, g3, be3);
        } else {
            conv3x3_kernel<64, 8, false, true, true, T, float, T><<<cg2, blk, 0, stream>>>(
                y64, w2, h, finalOut, ds + 128,
                ds, 1.0 / 204800.0, g1, be1, C48, 6, 8);
            add_relu_gn2_kernel<float, T><<<SLOT_QBLK, blk, 0, stream>>>(
                finalOut, zin, ds + 128, g2, be2, ds + 256);
            gn3_apply_kernel<float, T, float><<<SLOT_QBLK, blk, 0, stream>>>(
                finalOut, (const T*)nullptr, finalOut, (float*)nullptr, ds + 256, g3, be3);
        }
    };

    // slot 0: X=0, F0=f(0), G0=F0-0
    resnet(zcur, Fb, Gb, nullptr);
    gram_zero_kernel<<<1, 64, 0, stream>>>(gram, 0, 1);
    gram_update_kernel<T><<<dim3(75, 8), blk, 0, stream>>>(Gb, gram, 0, 1);

    // slot 1: X=F0, F1=f(F0), G1=F1-F0
    copy16_kernel<<<CHUNKS16, blk, 0, stream>>>((float4*)zcur, (const float4*)Fb);
    resnet(zcur, Fb + (size_t)SLOT, Gb + (size_t)SLOT, nullptr);
    gram_zero_kernel<<<1, 64, 0, stream>>>(gram, 1, 2);
    gram_update_kernel<T><<<dim3(75, 8), blk, 0, stream>>>(Gb, gram, 1, 2);

    for (int k = 2; k <= 24; k++) {
        int n = imin(k, 5);
        int j = k % 5;
        int nf = imin(k + 1, 5);
        solve_kernel<<<1, 64, 0, stream>>>(gram, alpha, n);
        // xk also zeroes gram row/col j (after solve consumed the old gram)
        xk_kernel<T><<<SLOT_QBLK, blk, 0, stream>>>(Fb, alpha, zcur, n, gram, j, nf);
        if (k < 24) {  // reference computes Fv at k=24 but never uses it
            resnet(zcur, Fb + (size_t)j * SLOT, Gb + (size_t)j * SLOT, nullptr);
            gram_update_kernel<T><<<dim3(75, 8), blk, 0, stream>>>(Gb, gram, j, nf);
        }
    }

    // z_star = zcur (= x_24); one extra f application -> fp32 scratch
    resnet(zcur, nullptr, nullptr, scratch);

    // final linear: [8,48,128,200] x [10,200]^T -> [8,48,128,10]
    fc_kernel<<<(BB * C48 * HH * 10) / 256, blk, 0, stream>>>(scratch, fcw, fcb, (float*)out);
}

extern "C" void kernel_launch(void* const* d_in, const int* in_sizes, int n_in,
                              void* d_out, int out_size, void* d_ws, size_t ws_size,
                              hipStream_t stream)
{
    const size_t STATB  = 9696 * 8 + 200 * 8 + 40 * 4;  // 79328 B
    const size_t need32 = BIGELEMS * 4 + STATB;  // ~524.4 MB: all-fp32 tier
    const size_t need16 = BIGELEMS * 2 + STATB;  // ~262.2 MB: bf16-storage tier

    if (ws_size >= need32) {
        run_pipeline<float>(d_in, (float*)d_out, d_ws, stream);
    } else if (ws_size >= need16) {
        run_pipeline<bf16_t>(d_in, (float*)d_out, d_ws, stream);
    }
    // else: workspace too small for any layout — nothing we can safely do
}

// Round 5
// 8957.292 us; speedup vs baseline: 2.6808x; 2.4619x over previous
//
#include <hip/hip_runtime.h>

#define BB   8
#define HH   128
#define WW   200
#define HWSZ 25600
#define C48  48
#define C64  64
#define NGRP 8
#define EPSV 1e-5f
#define LAMV 1e-4
#define SLOT 9830400          // BB*C48*HWSZ elements (one z/F/G slot)
#define DPB  1228800          // C48*HWSZ per-batch flat dim
#define Y64SZ 13107200        // BB*C64*HWSZ
#define BIGELEMS 131072000ull // 12*SLOT + Y64SZ

typedef unsigned short bf16_t;
typedef __attribute__((ext_vector_type(4))) short s4v;
typedef __attribute__((ext_vector_type(8))) short s8v;
typedef __attribute__((ext_vector_type(16))) float f32x16;

__device__ inline float b2f(bf16_t b) { return __uint_as_float(((unsigned)b) << 16); }
__device__ inline bf16_t f2b(float f) {
    unsigned u = __float_as_uint(f);
    unsigned r = u + 0x7fffu + ((u >> 16) & 1u);
    return (bf16_t)(r >> 16);
}
__device__ inline float4 ld4(const float* p) { return *(const float4*)p; }
__device__ inline float4 ld4(const bf16_t* p) {
    ushort4 u = *(const ushort4*)p;
    return make_float4(b2f(u.x), b2f(u.y), b2f(u.z), b2f(u.w));
}
__device__ inline void st4(bf16_t* p, float4 v) {
    ushort4 u; u.x = f2b(v.x); u.y = f2b(v.y); u.z = f2b(v.z); u.w = f2b(v.w);
    *(ushort4*)p = u;
}

// (mean, invstd) from f64 sums at use site
__device__ inline void ms_from(const double* __restrict__ ds, int pair, double invcnt,
                               float& mean, float& inv) {
    double s = ds[2 * pair], q = ds[2 * pair + 1];
    double m = s * invcnt;
    double v = q * invcnt - m * m;
    mean = (float)m;
    inv = (float)(1.0 / sqrt(v + (double)EPSV));
}

// ---------------- utility ----------------

__global__ void zero_kernel(float* __restrict__ p, int n) {
    int i = blockIdx.x * 256 + threadIdx.x;
    if (i < n) p[i] = 0.f;
}
__global__ void fill16_kernel(float4* __restrict__ p) {
    float4 z; z.x = z.y = z.z = z.w = 0.f;
    p[(size_t)blockIdx.x * 256 + threadIdx.x] = z;
}
__global__ void copy16_kernel(float4* __restrict__ dst, const float4* __restrict__ src) {
    size_t i = (size_t)blockIdx.x * 256 + threadIdx.x;
    dst[i] = src[i];
}

// ---------------- weight packing: [kc][tap][mt][lane][8] bf16 ----------------
__global__ void pack_kernel(const float* __restrict__ w, bf16_t* __restrict__ apk,
                            int CIN, int CO_real, int total) {
    int idx = blockIdx.x * 256 + threadIdx.x;
    if (idx >= total) return;
    int j   = idx & 7;
    int l   = (idx >> 3) & 63;
    int mt  = (idx >> 9) & 1;
    int tap = (idx >> 10) % 9;
    int kc  = idx / 9216;
    int co = mt * 32 + (l & 31);
    int ci = kc * 16 + (l >> 5) * 8 + j;
    float v = (co < CO_real) ? w[((size_t)co * CIN + ci) * 9 + tap] : 0.f;
    apk[idx] = f2b(v);
}

// ---------------- conv0 (1->48), NHWC fp32 raw out ----------------
__global__ __launch_bounds__(192) void conv0_kernel(
    const float* __restrict__ x, const float* __restrict__ w0,
    const float* __restrict__ b0, float* __restrict__ out)
{
    int tid = threadIdx.x;
    int c = tid % 48, pi = tid / 48;
    int px = blockIdx.x * 4 + pi;
    int b = px / HWSZ; int rem = px % HWSZ;
    int y = rem / WW, xx = rem % WW;
    const float* __restrict__ xp = x + (size_t)b * HWSZ;
    float acc = b0[c];
    #pragma unroll
    for (int dy = 0; dy < 3; dy++) {
        int gy = y + dy - 1;
        if ((unsigned)gy >= (unsigned)HH) continue;
        #pragma unroll
        for (int dx = 0; dx < 3; dx++) {
            int gx = xx + dx - 1;
            if ((unsigned)gx >= (unsigned)WW) continue;
            acc = fmaf(xp[gy * WW + gx], w0[c * 9 + dy * 3 + dx], acc);
        }
    }
    out[(size_t)px * 48 + c] = acc;
}

// ---------------- generic stats: sums (s,q) per (b,g) in f64 ----------------
// block = 2048 consecutive NHWC elems (one b). BSTRIDE=0 collapses b (BatchNorm).
template<int C, int Cg, int NG, int BSTRIDE, typename T>
__global__ __launch_bounds__(256) void stats_kernel(
    const T* __restrict__ src, double* __restrict__ dst, int blocksPerB)
{
    __shared__ float sm[NG * 2];
    int tid = threadIdx.x;
    if (tid < NG * 2) sm[tid] = 0.f;
    __syncthreads();
    int b = blockIdx.x / blocksPerB;
    size_t base = (size_t)blockIdx.x * 2048 + (size_t)tid * 8;
    int c0 = (int)(base % C);
    float4 vA = ld4(src + base);
    float4 vB = ld4(src + base + 4);
    float vv[8] = {vA.x, vA.y, vA.z, vA.w, vB.x, vB.y, vB.z, vB.w};
    float s = 0.f, q = 0.f;
    int gprev = c0 / Cg;
    #pragma unroll
    for (int e = 0; e < 8; e++) {
        int g = (c0 + e) / Cg;
        if (g != gprev) {
            atomicAdd(&sm[gprev * 2], s); atomicAdd(&sm[gprev * 2 + 1], q);
            s = 0.f; q = 0.f; gprev = g;
        }
        s += vv[e]; q += vv[e] * vv[e];
    }
    atomicAdd(&sm[gprev * 2], s); atomicAdd(&sm[gprev * 2 + 1], q);
    __syncthreads();
    if (tid < NG) {
        atomicAdd(&dst[(b * BSTRIDE + tid) * 2],     (double)sm[tid * 2]);
        atomicAdd(&dst[(b * BSTRIDE + tid) * 2 + 1], (double)sm[tid * 2 + 1]);
    }
}

// ---------------- BN apply: fp32 NHWC raw -> bf16 NHWC h ----------------
__global__ __launch_bounds__(256) void bn_apply_kernel(
    const float* __restrict__ src, bf16_t* __restrict__ dst,
    const float* __restrict__ gamma, const float* __restrict__ beta,
    const double* __restrict__ ds)
{
    __shared__ float gaT[48], beT[48];
    int tid = threadIdx.x;
    if (tid < 48) {
        float mean, inv; ms_from(ds, tid, 1.0 / 204800.0, mean, inv);
        float ga = gamma[tid] * inv;
        gaT[tid] = ga; beT[tid] = beta[tid] - mean * ga;
    }
    __syncthreads();
    size_t base = (size_t)blockIdx.x * 1024 + (size_t)tid * 4;
    int c0 = (int)(base % 48);
    float4 v = *(const float4*)(src + base);
    ushort4 o;
    o.x = f2b(fmaf(v.x, gaT[c0],     beT[c0]));
    o.y = f2b(fmaf(v.y, gaT[c0 + 1], beT[c0 + 1]));
    o.z = f2b(fmaf(v.z, gaT[c0 + 2], beT[c0 + 2]));
    o.w = f2b(fmaf(v.w, gaT[c0 + 3], beT[c0 + 3]));
    *(ushort4*)(dst + base) = o;
}

// ---------------- MFMA implicit-GEMM 3x3 conv ----------------
// grid (7 x-tiles of 32, 32 y-tiles of 4, 8 b); block 256 = 4 waves (one output row each).
// wave computes [64 co x 32 px] via 2 M-tiles of v_mfma_f32_32x32x16_bf16.
// FOLDGN: gn1 applied to input during LDS staging (halo stays 0 = correct SAME padding).
template<int CIN, int CIPAD, int CO, bool RELU, bool ADDH, bool FOLDGN>
__global__ __launch_bounds__(256) void conv_mfma_kernel(
    const bf16_t* __restrict__ in, const s8v* __restrict__ apk,
    const bf16_t* __restrict__ hadd, bf16_t* __restrict__ out,
    const double* __restrict__ dsPrev, const float* __restrict__ gPrev,
    const float* __restrict__ bPrev)
{
    constexpr int KC  = CIN / 16;
    constexpr int NCH = CIN / 4;
    const int tid  = threadIdx.x;
    const int lane = tid & 63;
    const int wv   = tid >> 6;
    const int x0 = blockIdx.x * 32;
    const int y0 = blockIdx.y * 4;
    const int b  = blockIdx.z;

    __shared__ __align__(16) bf16_t bt[6 * 34 * CIPAD];
    __shared__ __align__(16) float gaT[FOLDGN ? CIN : 4];
    __shared__ __align__(16) float beT[FOLDGN ? CIN : 4];

    if (FOLDGN) {
        if (tid < CIN) {
            float mean, inv;
            ms_from(dsPrev, b * NGRP + tid / (CIN / NGRP), 1.0 / 204800.0, mean, inv);
            float ga = gPrev[tid] * inv;
            gaT[tid] = ga; beT[tid] = bPrev[tid] - mean * ga;
        }
        __syncthreads();
    }
    // stage full input tile: rows y0-1..y0+4, cols x0-1..x0+32, all CIN (4-ci chunks)
    for (int i = tid; i < 6 * 34 * NCH; i += 256) {
        int ch = i % NCH, p = i / NCH;
        int r = p / 34, c = p - r * 34;
        int gy = y0 + r - 1, gx = x0 + c - 1;
        ushort4 v = make_ushort4(0, 0, 0, 0);
        if ((unsigned)gy < (unsigned)HH && (unsigned)gx < (unsigned)WW) {
            ushort4 raw = *(const ushort4*)(in + ((((size_t)b * HH + gy) * WW + gx) * CIN + ch * 4));
            if (FOLDGN) {
                float4 ga4 = *(const float4*)&gaT[ch * 4];
                float4 be4 = *(const float4*)&beT[ch * 4];
                v.x = f2b(fmaf(b2f(raw.x), ga4.x, be4.x));
                v.y = f2b(fmaf(b2f(raw.y), ga4.y, be4.y));
                v.z = f2b(fmaf(b2f(raw.z), ga4.z, be4.z));
                v.w = f2b(fmaf(b2f(raw.w), ga4.w, be4.w));
            } else v = raw;
        }
        *(ushort4*)(bt + p * CIPAD + ch * 4) = v;
    }
    __syncthreads();

    const int n = lane & 31, half = lane >> 5;
    f32x16 acc0, acc1;
    #pragma unroll
    for (int i = 0; i < 16; i++) { acc0[i] = 0.f; acc1[i] = 0.f; }

    for (int kc = 0; kc < KC; kc++) {
        s8v af[18];
        const s8v* ap = apk + (size_t)kc * 9 * 2 * 64 + lane;
        #pragma unroll
        for (int t = 0; t < 18; t++) af[t] = ap[t * 64];
        #pragma unroll
        for (int ky = 0; ky < 3; ky++)
        #pragma unroll
        for (int kx = 0; kx < 3; kx++) {
            const bf16_t* bp = bt + ((wv + ky) * 34 + n + kx) * CIPAD + kc * 16 + half * 8;
            s4v lo = *(const s4v*)bp;
            s4v hi = *(const s4v*)(bp + 4);
            s8v bfrag = __builtin_shufflevector(lo, hi, 0, 1, 2, 3, 4, 5, 6, 7);
            int t9 = (ky * 3 + kx) * 2;
            acc0 = __builtin_amdgcn_mfma_f32_32x32x16_bf16(af[t9],     bfrag, acc0, 0, 0, 0);
            acc1 = __builtin_amdgcn_mfma_f32_32x32x16_bf16(af[t9 + 1], bfrag, acc1, 0, 0, 0);
        }
    }
    int y = y0 + wv, xx = x0 + n;
    if (xx < WW) {
        size_t obase = (((size_t)b * HH + y) * WW + xx) * CO;
        #pragma unroll
        for (int r = 0; r < 16; r++) {
            int co0 = (r & 3) + 8 * (r >> 2) + 4 * half;
            {
                float v = acc0[r];
                if (RELU) v = fmaxf(v, 0.f);
                if (ADDH) v += b2f(hadd[obase + co0]);
                out[obase + co0] = f2b(v);
            }
            int co1 = 32 + co0;
            if (co1 < CO) {
                float v = acc1[r];
                if (RELU) v = fmaxf(v, 0.f);
                if (ADDH) v += b2f(hadd[obase + co1]);
                out[obase + co1] = f2b(v);
            }
        }
    }
}

// ---------------- v = relu(z + gn2(u)) in place on u, fused gn3 stats ----------------
__global__ __launch_bounds__(256) void add_relu_gn2_kernel(
    bf16_t* __restrict__ u, const bf16_t* __restrict__ z,
    const double* __restrict__ ds2, const float* __restrict__ g2,
    const float* __restrict__ b2, double* __restrict__ ds3)
{
    __shared__ float gaT[48], beT[48], sm[16];
    int tid = threadIdx.x;
    int b = blockIdx.x / 600;
    if (tid < 48) {
        float mean, inv; ms_from(ds2, b * NGRP + tid / 6, 1.0 / 153600.0, mean, inv);
        float ga = g2[tid] * inv;
        gaT[tid] = ga; beT[tid] = b2[tid] - mean * ga;
    }
    if (tid < 16) sm[tid] = 0.f;
    __syncthreads();
    size_t base = (size_t)blockIdx.x * 2048 + (size_t)tid * 8;
    int c0 = (int)(base % 48);
    float4 uA = ld4(u + base), uB = ld4(u + base + 4);
    float4 zA = ld4(z + base), zB = ld4(z + base + 4);
    float uu[8] = {uA.x, uA.y, uA.z, uA.w, uB.x, uB.y, uB.z, uB.w};
    float zz[8] = {zA.x, zA.y, zA.z, zA.w, zB.x, zB.y, zB.z, zB.w};
    float vv[8];
    #pragma unroll
    for (int e = 0; e < 8; e++) {
        int c = c0 + e;
        vv[e] = fmaxf(fmaf(uu[e], gaT[c], beT[c]) + zz[e], 0.f);
    }
    st4(u + base,     make_float4(vv[0], vv[1], vv[2], vv[3]));
    st4(u + base + 4, make_float4(vv[4], vv[5], vv[6], vv[7]));
    float s = 0.f, q = 0.f;
    int gprev = c0 / 6;
    #pragma unroll
    for (int e = 0; e < 8; e++) {
        int g = (c0 + e) / 6;
        if (g != gprev) {
            atomicAdd(&sm[gprev * 2], s); atomicAdd(&sm[gprev * 2 + 1], q);
            s = 0.f; q = 0.f; gprev = g;
        }
        s += vv[e]; q += vv[e] * vv[e];
    }
    atomicAdd(&sm[gprev * 2], s); atomicAdd(&sm[gprev * 2 + 1], q);
    __syncthreads();
    if (tid < 8) {
        atomicAdd(&ds3[(b * NGRP + tid) * 2],     (double)sm[tid * 2]);
        atomicAdd(&ds3[(b * NGRP + tid) * 2 + 1], (double)sm[tid * 2 + 1]);
    }
}

// ---------------- gn3 apply: F = gn3(v); optionally G = F - z ----------------
__global__ __launch_bounds__(256) void gn3_apply_kernel(
    const bf16_t* __restrict__ v, const bf16_t* __restrict__ z,
    bf16_t* __restrict__ F, bf16_t* __restrict__ G,
    const double* __restrict__ ds3, const float* __restrict__ g3,
    const float* __restrict__ b3)
{
    __shared__ float gaT[48], beT[48];
    int tid = threadIdx.x;
    int b = blockIdx.x / 600;
    if (tid < 48) {
        float mean, inv; ms_from(ds3, b * NGRP + tid / 6, 1.0 / 153600.0, mean, inv);
        float ga = g3[tid] * inv;
        gaT[tid] = ga; beT[tid] = b3[tid] - mean * ga;
    }
    __syncthreads();
    size_t base = (size_t)blockIdx.x * 2048 + (size_t)tid * 8;
    int c0 = (int)(base % 48);
    float4 vA = ld4(v + base), vB = ld4(v + base + 4);
    float rr[8] = {vA.x, vA.y, vA.z, vA.w, vB.x, vB.y, vB.z, vB.w};
    #pragma unroll
    for (int e = 0; e < 8; e++) rr[e] = fmaf(rr[e], gaT[c0 + e], beT[c0 + e]);
    st4(F + base,     make_float4(rr[0], rr[1], rr[2], rr[3]));
    st4(F + base + 4, make_float4(rr[4], rr[5], rr[6], rr[7]));
    if (G) {
        float4 zA = ld4(z + base), zB = ld4(z + base + 4);
        st4(G + base,     make_float4(rr[0] - zA.x, rr[1] - zA.y, rr[2] - zA.z, rr[3] - zA.w));
        st4(G + base + 4, make_float4(rr[4] - zB.x, rr[5] - zB.y, rr[6] - zB.z, rr[7] - zB.w));
    }
}

// ---------------- Anderson machinery ----------------

__global__ void gram_zero_kernel(double* __restrict__ gram, int j, int n) {
    int t = threadIdx.x;
    if (t < 8 * n) {
        int b = t / n, i = t - (t / n) * n;
        gram[b * 25 + j * 5 + i] = 0.0;
        gram[b * 25 + i * 5 + j] = 0.0;
    }
}

__global__ __launch_bounds__(256) void gram_update_kernel(
    const bf16_t* __restrict__ Gbase, double* __restrict__ gram, int j, int n)
{
    __shared__ double red[8];
    int b = blockIdx.y;
    const bf16_t* __restrict__ base = Gbase + (size_t)b * DPB;
    const bf16_t* __restrict__ gj = base + (size_t)j * SLOT;
    size_t f4s = (size_t)blockIdx.x * 4096 + threadIdx.x;
    double dot[5] = {0.0, 0.0, 0.0, 0.0, 0.0};
    for (int it = 0; it < 16; it++) {
        size_t p = (f4s + (size_t)it * 256) * 4;
        float4 gv = ld4(gj + p);
        #pragma unroll
        for (int i = 0; i < 5; i++) {
            if (i < n) {
                float4 gi = ld4(base + (size_t)i * SLOT + p);
                dot[i] += (double)gv.x * gi.x + (double)gv.y * gi.y
                        + (double)gv.z * gi.z + (double)gv.w * gi.w;
            }
        }
    }
    #pragma unroll
    for (int i = 0; i < 5; i++) {
        if (i >= n) continue;
        double s = dot[i];
        #pragma unroll
        for (int off = 32; off > 0; off >>= 1) s += __shfl_down(s, off);
        __syncthreads();
        if ((threadIdx.x & 63) == 0) red[threadIdx.x >> 6] = s;
        __syncthreads();
        if (threadIdx.x == 0) {
            double S = red[0] + red[1] + red[2] + red[3];
            atomicAdd(&gram[b * 25 + j * 5 + i], S);
            if (i != j) atomicAdd(&gram[b * 25 + i * 5 + j], S);
        }
    }
}

__global__ void solve_kernel(const double* __restrict__ gram, float* __restrict__ alpha, int n) {
    int b = threadIdx.x;
    if (b >= BB) return;
    const int m = n + 1;
    double A[6][7];
    for (int i = 0; i < m; i++)
        for (int jj = 0; jj <= m; jj++) A[i][jj] = 0.0;
    for (int i = 1; i < m; i++) { A[0][i] = 1.0; A[i][0] = 1.0; }
    for (int i = 1; i < m; i++)
        for (int jj = 1; jj < m; jj++)
            A[i][jj] = gram[b * 25 + (i - 1) * 5 + (jj - 1)] + ((i == jj) ? LAMV : 0.0);
    A[0][m] = 1.0;
    for (int col = 0; col < m; col++) {
        int piv = col; double best = fabs(A[col][col]);
        for (int rr = col + 1; rr < m; rr++) {
            double tv = fabs(A[rr][col]);
            if (tv > best) { best = tv; piv = rr; }
        }
        if (piv != col)
            for (int cc = col; cc <= m; cc++) {
                double tmp = A[col][cc]; A[col][cc] = A[piv][cc]; A[piv][cc] = tmp;
            }
        double invp = 1.0 / A[col][col];
        for (int cc = col; cc <= m; cc++) A[col][cc] *= invp;
        for (int rr = 0; rr < m; rr++) {
            if (rr == col) continue;
            double f = A[rr][col];
            if (f != 0.0)
                for (int cc = col; cc <= m; cc++) A[rr][cc] = fma(-f, A[col][cc], A[rr][cc]);
        }
    }
    for (int i = 0; i < n; i++) alpha[b * 5 + i] = (float)A[i + 1][m];
}

__global__ __launch_bounds__(256) void xk_kernel(
    const bf16_t* __restrict__ Fb, const float* __restrict__ alpha,
    bf16_t* __restrict__ zcur, int n, double* __restrict__ gram, int jz, int nf)
{
    if (blockIdx.x == 0 && threadIdx.x < 8 * nf) {
        int b = threadIdx.x / nf, i = threadIdx.x % nf;
        gram[b * 25 + jz * 5 + i] = 0.0;
        gram[b * 25 + i * 5 + jz] = 0.0;
    }
    size_t idx = ((size_t)blockIdx.x * 256 + threadIdx.x) * 4;
    int b = (int)(idx / DPB);
    float4 s; s.x = s.y = s.z = s.w = 0.f;
    #pragma unroll
    for (int j = 0; j < 5; j++) {
        if (j < n) {
            float al = alpha[b * 5 + j];
            float4 f = ld4(Fb + (size_t)j * SLOT + idx);
            s.x = fmaf(f.x, al, s.x); s.y = fmaf(f.y, al, s.y);
            s.z = fmaf(f.z, al, s.z); s.w = fmaf(f.w, al, s.w);
        }
    }
    st4(zcur + idx, s);
}

// ---------------- final linear (NHWC bf16 in) ----------------
__global__ __launch_bounds__(512) void fc_kernel(
    const bf16_t* __restrict__ zf, const float* __restrict__ fw,
    const float* __restrict__ fb, float* __restrict__ out)
{
    __shared__ bf16_t row[9600];
    __shared__ float fwT[2000];
    int tid = threadIdx.x;
    int b = blockIdx.x >> 7, hh = blockIdx.x & 127;
    size_t base = (((size_t)b * HH + hh) * WW) * 48;
    for (int i = tid; i < 2400; i += 512)
        *(ushort4*)&row[i * 4] = *(const ushort4*)(zf + base + (size_t)i * 4);
    for (int i = tid; i < 2000; i += 512) fwT[i] = fw[i];
    __syncthreads();
    if (tid < 480) {
        int c = tid % 48, o = tid / 48;
        float acc = fb[o];
        #pragma unroll 4
        for (int w = 0; w < 200; w++)
            acc = fmaf(b2f(row[w * 48 + c]), fwT[o * 200 + w], acc);
        out[(((size_t)b * 48 + c) * HH + hh) * 10 + o] = acc;
    }
}

// ---------------- host ----------------

static inline int imin(int a, int b) { return a < b ? a : b; }

extern "C" void kernel_launch(void* const* d_in, const int* in_sizes, int n_in,
                              void* d_out, int out_size, void* d_ws, size_t ws_size,
                              hipStream_t stream)
{
    const float* x   = (const float*)d_in[0];
    const float* w0  = (const float*)d_in[1];
    const float* b0  = (const float*)d_in[2];
    const float* bng = (const float*)d_in[3];
    const float* bnb = (const float*)d_in[4];
    const float* w1  = (const float*)d_in[5];
    const float* w2  = (const float*)d_in[6];
    const float* g1  = (const float*)d_in[7];
    const float* be1 = (const float*)d_in[8];
    const float* g2  = (const float*)d_in[9];
    const float* be2 = (const float*)d_in[10];
    const float* g3  = (const float*)d_in[11];
    const float* be3 = (const float*)d_in[12];
    const float* fcw = (const float*)d_in[13];
    const float* fcb = (const float*)d_in[14];
    float* out = (float*)d_out;

    bf16_t* h    = (bf16_t*)d_ws;           // SLOT    (NHWC)
    bf16_t* zcur = h + (size_t)SLOT;        // SLOT
    bf16_t* y64  = zcur + (size_t)SLOT;     // Y64SZ
    bf16_t* Fb   = y64 + (size_t)Y64SZ;     // 5*SLOT
    bf16_t* Gb   = Fb + 5 * (size_t)SLOT;   // 5*SLOT
    double* dstats = (double*)((char*)d_ws + BIGELEMS * 2);  // 9696 dbl: BN 96 + 25*384
    double* gram   = dstats + 9696;                          // 200 dbl
    float*  alpha  = (float*)(gram + 200);                   // 40 f
    bf16_t* apk1   = (bf16_t*)(alpha + 40);                  // 27648
    bf16_t* apk2   = apk1 + 27648;                           // 36864
    float*  scratch = (float*)Gb;  // conv0 raw fp32, SLOT floats == G0+G1 bytes (dead then)

    const size_t need = BIGELEMS * 2 + 9696 * 8 + 200 * 8 + 40 * 4 + (27648 + 36864) * 2;
    if (ws_size < need) return;

    const dim3 blk(256);
    const int SLOT_QBLK = SLOT / 4 / 256;   // 9600
    const int CHUNKS16  = SLOT * 2 / 16 / 256;  // 4800

    zero_kernel<<<(19792 + 255) / 256, blk, 0, stream>>>((float*)dstats, 19792);
    pack_kernel<<<108, blk, 0, stream>>>(w1, apk1, 48, 64, 27648);
    pack_kernel<<<144, blk, 0, stream>>>(w2, apk2, 64, 48, 36864);
    fill16_kernel<<<CHUNKS16, blk, 0, stream>>>((float4*)zcur);

    // h = BN(conv0(x)+b0) in NHWC bf16
    conv0_kernel<<<BB * HWSZ / 4, dim3(192), 0, stream>>>(x, w0, b0, scratch);
    stats_kernel<48, 1, 48, 0, float><<<SLOT / 2048, blk, 0, stream>>>(scratch, dstats, SLOT / 2048);
    bn_apply_kernel<<<SLOT / 1024, blk, 0, stream>>>(scratch, h, bng, bnb, dstats);

    int call = 0;
    auto resnet = [&](const bf16_t* zin, bf16_t* Fdst, bf16_t* Gdst) {
        double* ds = dstats + 96 + 384 * call;  // ds1 = +0 (64 pairs), ds2 = +128, ds3 = +256
        call++;
        dim3 cg(7, 32, BB);
        conv_mfma_kernel<48, 52, 64, true, false, false><<<cg, blk, 0, stream>>>(
            zin, (const s8v*)apk1, nullptr, y64, nullptr, nullptr, nullptr);
        stats_kernel<64, 8, 8, 8, bf16_t><<<Y64SZ / 2048, blk, 0, stream>>>(y64, ds, 800);
        conv_mfma_kernel<64, 68, 48, false, true, true><<<cg, blk, 0, stream>>>(
            y64, (const s8v*)apk2, h, Fdst, ds, g1, be1);
        stats_kernel<48, 6, 8, 8, bf16_t><<<SLOT / 2048, blk, 0, stream>>>(Fdst, ds + 128, 600);
        add_relu_gn2_kernel<<<SLOT / 2048, blk, 0, stream>>>(Fdst, zin, ds + 128, g2, be2, ds + 256);
        gn3_apply_kernel<<<SLOT / 2048, blk, 0, stream>>>(Fdst, zin, Fdst, Gdst, ds + 256, g3, be3);
    };

    // slot 0: X=0, F0=f(0), G0=F0
    resnet(zcur, Fb, Gb);
    gram_zero_kernel<<<1, 64, 0, stream>>>(gram, 0, 1);
    gram_update_kernel<<<dim3(75, 8), blk, 0, stream>>>(Gb, gram, 0, 1);

    // slot 1: X=F0, F1=f(F0), G1=F1-F0
    copy16_kernel<<<CHUNKS16, blk, 0, stream>>>((float4*)zcur, (const float4*)Fb);
    resnet(zcur, Fb + (size_t)SLOT, Gb + (size_t)SLOT);
    gram_zero_kernel<<<1, 64, 0, stream>>>(gram, 1, 2);
    gram_update_kernel<<<dim3(75, 8), blk, 0, stream>>>(Gb, gram, 1, 2);

    for (int k = 2; k <= 24; k++) {
        int n = imin(k, 5);
        int j = k % 5;
        int nf = imin(k + 1, 5);
        solve_kernel<<<1, 64, 0, stream>>>(gram, alpha, n);
        xk_kernel<<<SLOT_QBLK, blk, 0, stream>>>(Fb, alpha, zcur, n, gram, j, nf);
        if (k < 24) {  // reference computes Fv at k=24 but never uses it
            resnet(zcur, Fb + (size_t)j * SLOT, Gb + (size_t)j * SLOT);
            gram_update_kernel<<<dim3(75, 8), blk, 0, stream>>>(Gb, gram, j, nf);
        }
    }

    // z_star = zcur; one extra f application into F slot 0 (no G)
    resnet(zcur, Fb, nullptr);

    // final linear: NHWC [8,128,200,48] x fw[10,200] -> out [8,48,128,10]
    fc_kernel<<<BB * HH, dim3(512), 0, stream>>>(Fb, fcw, fcb, out);
}

// Round 6
// 6104.774 us; speedup vs baseline: 3.9334x; 1.4673x over previous
//
#include <hip/hip_runtime.h>

#define BB   8
#define HH   128
#define WW   200
#define HWSZ 25600
#define C48  48
#define C64  64
#define NGRP 8
#define EPSV 1e-5f
#define LAMV 1e-4
#define SLOT 9830400          // BB*C48*HWSZ elements (one z/F/G slot)
#define DPB  1228800          // C48*HWSZ per-batch flat dim
#define Y64SZ 13107200        // BB*C64*HWSZ
#define BIGELEMS 131072000ull // 12*SLOT + Y64SZ

typedef unsigned short bf16_t;
typedef __attribute__((ext_vector_type(4))) short s4v;
typedef __attribute__((ext_vector_type(8))) short s8v;
typedef __attribute__((ext_vector_type(16))) float f32x16;

__device__ inline float b2f(bf16_t b) { return __uint_as_float(((unsigned)b) << 16); }
__device__ inline bf16_t f2b(float f) {
    unsigned u = __float_as_uint(f);
    unsigned r = u + 0x7fffu + ((u >> 16) & 1u);
    return (bf16_t)(r >> 16);
}
__device__ inline float ldS(const float* p) { return *p; }
__device__ inline float ldS(const bf16_t* p) { return b2f(*p); }
__device__ inline float4 ld4(const float* p) { return *(const float4*)p; }
__device__ inline float4 ld4(const bf16_t* p) {
    ushort4 u = *(const ushort4*)p;
    return make_float4(b2f(u.x), b2f(u.y), b2f(u.z), b2f(u.w));
}
__device__ inline void st4(bf16_t* p, float4 v) {
    ushort4 u; u.x = f2b(v.x); u.y = f2b(v.y); u.z = f2b(v.z); u.w = f2b(v.w);
    *(ushort4*)p = u;
}

// (mean, invstd) from f64 sums at use site
__device__ inline void ms_from(const double* __restrict__ ds, int pair, double invcnt,
                               float& mean, float& inv) {
    double s = ds[2 * pair], q = ds[2 * pair + 1];
    double m = s * invcnt;
    double v = q * invcnt - m * m;
    mean = (float)m;
    inv = (float)(1.0 / sqrt(v + (double)EPSV));
}

// ---------------- utility ----------------

__global__ void zero_kernel(float* __restrict__ p, int n) {
    int i = blockIdx.x * 256 + threadIdx.x;
    if (i < n) p[i] = 0.f;
}
__global__ void fill16_kernel(float4* __restrict__ p) {
    float4 z; z.x = z.y = z.z = z.w = 0.f;
    p[(size_t)blockIdx.x * 256 + threadIdx.x] = z;
}
__global__ void copy16_kernel(float4* __restrict__ dst, const float4* __restrict__ src) {
    size_t i = (size_t)blockIdx.x * 256 + threadIdx.x;
    dst[i] = src[i];
}

// ---------------- weight packing: [kc][tap][mt][lane][8] bf16 ----------------
__global__ void pack_kernel(const float* __restrict__ w, bf16_t* __restrict__ apk,
                            int CIN, int CO_real, int total) {
    int idx = blockIdx.x * 256 + threadIdx.x;
    if (idx >= total) return;
    int j   = idx & 7;
    int l   = (idx >> 3) & 63;
    int mt  = (idx >> 9) & 1;
    int tap = (idx >> 10) % 9;
    int kc  = idx / 9216;
    int co = mt * 32 + (l & 31);
    int ci = kc * 16 + (l >> 5) * 8 + j;
    float v = (co < CO_real) ? w[((size_t)co * CIN + ci) * 9 + tap] : 0.f;
    apk[idx] = f2b(v);
}

// ---------------- conv0 (1->48), NHWC fp32 raw out ----------------
__global__ __launch_bounds__(192) void conv0_kernel(
    const float* __restrict__ x, const float* __restrict__ w0,
    const float* __restrict__ b0, float* __restrict__ out)
{
    int tid = threadIdx.x;
    int c = tid % 48, pi = tid / 48;
    int px = blockIdx.x * 4 + pi;
    int b = px / HWSZ; int rem = px % HWSZ;
    int y = rem / WW, xx = rem % WW;
    const float* __restrict__ xp = x + (size_t)b * HWSZ;
    float acc = b0[c];
    #pragma unroll
    for (int dy = 0; dy < 3; dy++) {
        int gy = y + dy - 1;
        if ((unsigned)gy >= (unsigned)HH) continue;
        #pragma unroll
        for (int dx = 0; dx < 3; dx++) {
            int gx = xx + dx - 1;
            if ((unsigned)gx >= (unsigned)WW) continue;
            acc = fmaf(xp[gy * WW + gx], w0[c * 9 + dy * 3 + dx], acc);
        }
    }
    out[(size_t)px * 48 + c] = acc;
}

// ---------------- channel-phased stats: sums (s,q) per (b,g), f64 native atomics ----------------
// block = 4*C threads: c = tid%C fixed per thread -> register accumulation, no atomics
// until ONE native f64 atomic pair per (block, group). grid (NB, BB), pxPerBlock px each.
template<int C, int Cg, int NG, int BSTRIDE, typename T>
__global__ void stats_kernel(const T* __restrict__ src, double* __restrict__ dst, int pxPerBlock)
{
    __shared__ float ss[4 * C], qq[4 * C];
    const int tid = threadIdx.x;
    const int c = tid % C, r = tid / C;
    const int b = blockIdx.y;
    const size_t base = ((size_t)b * HWSZ + (size_t)blockIdx.x * pxPerBlock) * C + c;
    float s = 0.f, q = 0.f;
    for (int p = r; p < pxPerBlock; p += 4) {
        float v = ldS(src + base + (size_t)p * C);
        s += v; q += v * v;
    }
    ss[tid] = s; qq[tid] = q;
    __syncthreads();
    if (tid < C) {
        s = ss[tid] + ss[tid + C] + ss[tid + 2 * C] + ss[tid + 3 * C];
        q = qq[tid] + qq[tid + C] + qq[tid + 2 * C] + qq[tid + 3 * C];
        ss[tid] = s; qq[tid] = q;
    }
    __syncthreads();
    if (tid < NG) {
        float S = 0.f, Q = 0.f;
        #pragma unroll
        for (int j = 0; j < Cg; j++) { S += ss[tid * Cg + j]; Q += qq[tid * Cg + j]; }
        unsafeAtomicAdd(&dst[(b * BSTRIDE + tid) * 2],     (double)S);
        unsafeAtomicAdd(&dst[(b * BSTRIDE + tid) * 2 + 1], (double)Q);
    }
}

// ---------------- BN apply: fp32 NHWC raw -> bf16 NHWC h ----------------
__global__ __launch_bounds__(256) void bn_apply_kernel(
    const float* __restrict__ src, bf16_t* __restrict__ dst,
    const float* __restrict__ gamma, const float* __restrict__ beta,
    const double* __restrict__ ds)
{
    __shared__ float gaT[48], beT[48];
    int tid = threadIdx.x;
    if (tid < 48) {
        float mean, inv; ms_from(ds, tid, 1.0 / 204800.0, mean, inv);
        float ga = gamma[tid] * inv;
        gaT[tid] = ga; beT[tid] = beta[tid] - mean * ga;
    }
    __syncthreads();
    size_t base = (size_t)blockIdx.x * 1024 + (size_t)tid * 4;
    int c0 = (int)(base % 48);
    float4 v = *(const float4*)(src + base);
    ushort4 o;
    o.x = f2b(fmaf(v.x, gaT[c0],     beT[c0]));
    o.y = f2b(fmaf(v.y, gaT[c0 + 1], beT[c0 + 1]));
    o.z = f2b(fmaf(v.z, gaT[c0 + 2], beT[c0 + 2]));
    o.w = f2b(fmaf(v.w, gaT[c0 + 3], beT[c0 + 3]));
    *(ushort4*)(dst + base) = o;
}

// ---------------- MFMA implicit-GEMM 3x3 conv ----------------
// grid (7 x-tiles of 32, 32 y-tiles of 4, 8 b); block 256 = 4 waves (one output row each).
// wave computes [64 co x 32 px] via 2 M-tiles of v_mfma_f32_32x32x16_bf16.
template<int CIN, int CIPAD, int CO, bool RELU, bool ADDH, bool FOLDGN>
__global__ __launch_bounds__(256) void conv_mfma_kernel(
    const bf16_t* __restrict__ in, const s8v* __restrict__ apk,
    const bf16_t* __restrict__ hadd, bf16_t* __restrict__ out,
    const double* __restrict__ dsPrev, const float* __restrict__ gPrev,
    const float* __restrict__ bPrev)
{
    constexpr int KC  = CIN / 16;
    constexpr int NCH = CIN / 4;
    const int tid  = threadIdx.x;
    const int lane = tid & 63;
    const int wv   = tid >> 6;
    const int x0 = blockIdx.x * 32;
    const int y0 = blockIdx.y * 4;
    const int b  = blockIdx.z;

    __shared__ __align__(16) bf16_t bt[6 * 34 * CIPAD];
    __shared__ __align__(16) float gaT[FOLDGN ? CIN : 4];
    __shared__ __align__(16) float beT[FOLDGN ? CIN : 4];

    if (FOLDGN) {
        if (tid < CIN) {
            float mean, inv;
            ms_from(dsPrev, b * NGRP + tid / (CIN / NGRP), 1.0 / 204800.0, mean, inv);
            float ga = gPrev[tid] * inv;
            gaT[tid] = ga; beT[tid] = bPrev[tid] - mean * ga;
        }
        __syncthreads();
    }
    for (int i = tid; i < 6 * 34 * NCH; i += 256) {
        int ch = i % NCH, p = i / NCH;
        int r = p / 34, c = p - r * 34;
        int gy = y0 + r - 1, gx = x0 + c - 1;
        ushort4 v = make_ushort4(0, 0, 0, 0);
        if ((unsigned)gy < (unsigned)HH && (unsigned)gx < (unsigned)WW) {
            ushort4 raw = *(const ushort4*)(in + ((((size_t)b * HH + gy) * WW + gx) * CIN + ch * 4));
            if (FOLDGN) {
                float4 ga4 = *(const float4*)&gaT[ch * 4];
                float4 be4 = *(const float4*)&beT[ch * 4];
                v.x = f2b(fmaf(b2f(raw.x), ga4.x, be4.x));
                v.y = f2b(fmaf(b2f(raw.y), ga4.y, be4.y));
                v.z = f2b(fmaf(b2f(raw.z), ga4.z, be4.z));
                v.w = f2b(fmaf(b2f(raw.w), ga4.w, be4.w));
            } else v = raw;
        }
        *(ushort4*)(bt + p * CIPAD + ch * 4) = v;
    }
    __syncthreads();

    const int n = lane & 31, half = lane >> 5;
    f32x16 acc0, acc1;
    #pragma unroll
    for (int i = 0; i < 16; i++) { acc0[i] = 0.f; acc1[i] = 0.f; }

    for (int kc = 0; kc < KC; kc++) {
        s8v af[18];
        const s8v* ap = apk + (size_t)kc * 9 * 2 * 64 + lane;
        #pragma unroll
        for (int t = 0; t < 18; t++) af[t] = ap[t * 64];
        #pragma unroll
        for (int ky = 0; ky < 3; ky++)
        #pragma unroll
        for (int kx = 0; kx < 3; kx++) {
            const bf16_t* bp = bt + ((wv + ky) * 34 + n + kx) * CIPAD + kc * 16 + half * 8;
            s4v lo = *(const s4v*)bp;
            s4v hi = *(const s4v*)(bp + 4);
            s8v bfrag = __builtin_shufflevector(lo, hi, 0, 1, 2, 3, 4, 5, 6, 7);
            int t9 = (ky * 3 + kx) * 2;
            acc0 = __builtin_amdgcn_mfma_f32_32x32x16_bf16(af[t9],     bfrag, acc0, 0, 0, 0);
            acc1 = __builtin_amdgcn_mfma_f32_32x32x16_bf16(af[t9 + 1], bfrag, acc1, 0, 0, 0);
        }
    }
    int y = y0 + wv, xx = x0 + n;
    if (xx < WW) {
        size_t obase = (((size_t)b * HH + y) * WW + xx) * CO;
        #pragma unroll
        for (int r = 0; r < 16; r++) {
            int co0 = (r & 3) + 8 * (r >> 2) + 4 * half;
            {
                float v = acc0[r];
                if (RELU) v = fmaxf(v, 0.f);
                if (ADDH) v += b2f(hadd[obase + co0]);
                out[obase + co0] = f2b(v);
            }
            int co1 = 32 + co0;
            if (co1 < CO) {
                float v = acc1[r];
                if (RELU) v = fmaxf(v, 0.f);
                if (ADDH) v += b2f(hadd[obase + co1]);
                out[obase + co1] = f2b(v);
            }
        }
    }
}

// ---------------- v = relu(z + gn2(u)) in place on u, channel-phased gn3 stats ----------------
// block 192 = 4 rows x 48 channels; grid (NB, BB)
__global__ __launch_bounds__(192) void add_relu_gn2_kernel(
    bf16_t* __restrict__ u, const bf16_t* __restrict__ z,
    const double* __restrict__ ds2, const float* __restrict__ g2,
    const float* __restrict__ b2, double* __restrict__ ds3, int pxPerBlock)
{
    __shared__ float ss[192], qq[192];
    const int tid = threadIdx.x;
    const int c = tid % 48, r = tid / 48;
    const int b = blockIdx.y;
    float mean, inv; ms_from(ds2, b * NGRP + c / 6, 1.0 / 153600.0, mean, inv);
    const float ga = g2[c] * inv;
    const float be = b2[c] - mean * ga;
    const size_t base = ((size_t)b * HWSZ + (size_t)blockIdx.x * pxPerBlock) * 48 + c;
    float s = 0.f, q = 0.f;
    for (int p = r; p < pxPerBlock; p += 4) {
        size_t idx = base + (size_t)p * 48;
        float v = fmaxf(fmaf(b2f(u[idx]), ga, be) + b2f(z[idx]), 0.f);
        u[idx] = f2b(v);
        s += v; q += v * v;
    }
    ss[tid] = s; qq[tid] = q;
    __syncthreads();
    if (tid < 48) {
        s = ss[tid] + ss[tid + 48] + ss[tid + 96] + ss[tid + 144];
        q = qq[tid] + qq[tid + 48] + qq[tid + 96] + qq[tid + 144];
        ss[tid] = s; qq[tid] = q;
    }
    __syncthreads();
    if (tid < NGRP) {
        float S = 0.f, Q = 0.f;
        #pragma unroll
        for (int j = 0; j < 6; j++) { S += ss[tid * 6 + j]; Q += qq[tid * 6 + j]; }
        unsafeAtomicAdd(&ds3[(b * NGRP + tid) * 2],     (double)S);
        unsafeAtomicAdd(&ds3[(b * NGRP + tid) * 2 + 1], (double)Q);
    }
}

// ---------------- gn3 apply: F = gn3(v); optionally G = F - z ----------------
__global__ __launch_bounds__(256) void gn3_apply_kernel(
    const bf16_t* __restrict__ v, const bf16_t* __restrict__ z,
    bf16_t* __restrict__ F, bf16_t* __restrict__ G,
    const double* __restrict__ ds3, const float* __restrict__ g3,
    const float* __restrict__ b3)
{
    __shared__ float gaT[48], beT[48];
    int tid = threadIdx.x;
    int b = blockIdx.x / 600;
    if (tid < 48) {
        float mean, inv; ms_from(ds3, b * NGRP + tid / 6, 1.0 / 153600.0, mean, inv);
        float ga = g3[tid] * inv;
        gaT[tid] = ga; beT[tid] = b3[tid] - mean * ga;
    }
    __syncthreads();
    size_t base = (size_t)blockIdx.x * 2048 + (size_t)tid * 8;
    int c0 = (int)(base % 48);
    float4 vA = ld4(v + base), vB = ld4(v + base + 4);
    float rr[8] = {vA.x, vA.y, vA.z, vA.w, vB.x, vB.y, vB.z, vB.w};
    #pragma unroll
    for (int e = 0; e < 8; e++) rr[e] = fmaf(rr[e], gaT[c0 + e], beT[c0 + e]);
    st4(F + base,     make_float4(rr[0], rr[1], rr[2], rr[3]));
    st4(F + base + 4, make_float4(rr[4], rr[5], rr[6], rr[7]));
    if (G) {
        float4 zA = ld4(z + base), zB = ld4(z + base + 4);
        st4(G + base,     make_float4(rr[0] - zA.x, rr[1] - zA.y, rr[2] - zA.z, rr[3] - zA.w));
        st4(G + base + 4, make_float4(rr[4] - zB.x, rr[5] - zB.y, rr[6] - zB.z, rr[7] - zB.w));
    }
}

// ---------------- Anderson machinery ----------------

__global__ void gram_zero_kernel(double* __restrict__ gram, int j, int n) {
    int t = threadIdx.x;
    if (t < 8 * n) {
        int b = t / n, i = t - (t / n) * n;
        gram[b * 25 + j * 5 + i] = 0.0;
        gram[b * 25 + i * 5 + j] = 0.0;
    }
}

__global__ __launch_bounds__(256) void gram_update_kernel(
    const bf16_t* __restrict__ Gbase, double* __restrict__ gram, int j, int n)
{
    __shared__ double red[8];
    int b = blockIdx.y;
    const bf16_t* __restrict__ base = Gbase + (size_t)b * DPB;
    const bf16_t* __restrict__ gj = base + (size_t)j * SLOT;
    size_t f4s = (size_t)blockIdx.x * 4096 + threadIdx.x;
    double dot[5] = {0.0, 0.0, 0.0, 0.0, 0.0};
    for (int it = 0; it < 16; it++) {
        size_t p = (f4s + (size_t)it * 256) * 4;
        float4 gv = ld4(gj + p);
        #pragma unroll
        for (int i = 0; i < 5; i++) {
            if (i < n) {
                float4 gi = ld4(base + (size_t)i * SLOT + p);
                dot[i] += (double)gv.x * gi.x + (double)gv.y * gi.y
                        + (double)gv.z * gi.z + (double)gv.w * gi.w;
            }
        }
    }
    #pragma unroll
    for (int i = 0; i < 5; i++) {
        if (i >= n) continue;
        double s = dot[i];
        #pragma unroll
        for (int off = 32; off > 0; off >>= 1) s += __shfl_down(s, off);
        __syncthreads();
        if ((threadIdx.x & 63) == 0) red[threadIdx.x >> 6] = s;
        __syncthreads();
        if (threadIdx.x == 0) {
            double S = red[0] + red[1] + red[2] + red[3];
            unsafeAtomicAdd(&gram[b * 25 + j * 5 + i], S);
            if (i != j) unsafeAtomicAdd(&gram[b * 25 + i * 5 + j], S);
        }
    }
}

__global__ void solve_kernel(const double* __restrict__ gram, float* __restrict__ alpha, int n) {
    int b = threadIdx.x;
    if (b >= BB) return;
    const int m = n + 1;
    double A[6][7];
    for (int i = 0; i < m; i++)
        for (int jj = 0; jj <= m; jj++) A[i][jj] = 0.0;
    for (int i = 1; i < m; i++) { A[0][i] = 1.0; A[i][0] = 1.0; }
    for (int i = 1; i < m; i++)
        for (int jj = 1; jj < m; jj++)
            A[i][jj] = gram[b * 25 + (i - 1) * 5 + (jj - 1)] + ((i == jj) ? LAMV : 0.0);
    A[0][m] = 1.0;
    for (int col = 0; col < m; col++) {
        int piv = col; double best = fabs(A[col][col]);
        for (int rr = col + 1; rr < m; rr++) {
            double tv = fabs(A[rr][col]);
            if (tv > best) { best = tv; piv = rr; }
        }
        if (piv != col)
            for (int cc = col; cc <= m; cc++) {
                double tmp = A[col][cc]; A[col][cc] = A[piv][cc]; A[piv][cc] = tmp;
            }
        double invp = 1.0 / A[col][col];
        for (int cc = col; cc <= m; cc++) A[col][cc] *= invp;
        for (int rr = 0; rr < m; rr++) {
            if (rr == col) continue;
            double f = A[rr][col];
            if (f != 0.0)
                for (int cc = col; cc <= m; cc++) A[rr][cc] = fma(-f, A[col][cc], A[rr][cc]);
        }
    }
    for (int i = 0; i < n; i++) alpha[b * 5 + i] = (float)A[i + 1][m];
}

__global__ __launch_bounds__(256) void xk_kernel(
    const bf16_t* __restrict__ Fb, const float* __restrict__ alpha,
    bf16_t* __restrict__ zcur, int n, double* __restrict__ gram, int jz, int nf)
{
    if (blockIdx.x == 0 && threadIdx.x < 8 * nf) {
        int b = threadIdx.x / nf, i = threadIdx.x % nf;
        gram[b * 25 + jz * 5 + i] = 0.0;
        gram[b * 25 + i * 5 + jz] = 0.0;
    }
    size_t idx = ((size_t)blockIdx.x * 256 + threadIdx.x) * 4;
    int b = (int)(idx / DPB);
    float4 s; s.x = s.y = s.z = s.w = 0.f;
    #pragma unroll
    for (int j = 0; j < 5; j++) {
        if (j < n) {
            float al = alpha[b * 5 + j];
            float4 f = ld4(Fb + (size_t)j * SLOT + idx);
            s.x = fmaf(f.x, al, s.x); s.y = fmaf(f.y, al, s.y);
            s.z = fmaf(f.z, al, s.z); s.w = fmaf(f.w, al, s.w);
        }
    }
    st4(zcur + idx, s);
}

// ---------------- final linear (NHWC bf16 in) ----------------
__global__ __launch_bounds__(512) void fc_kernel(
    const bf16_t* __restrict__ zf, const float* __restrict__ fw,
    const float* __restrict__ fb, float* __restrict__ out)
{
    __shared__ bf16_t row[9600];
    __shared__ float fwT[2000];
    int tid = threadIdx.x;
    int b = blockIdx.x >> 7, hh = blockIdx.x & 127;
    size_t base = (((size_t)b * HH + hh) * WW) * 48;
    for (int i = tid; i < 2400; i += 512)
        *(ushort4*)&row[i * 4] = *(const ushort4*)(zf + base + (size_t)i * 4);
    for (int i = tid; i < 2000; i += 512) fwT[i] = fw[i];
    __syncthreads();
    if (tid < 480) {
        int c = tid % 48, o = tid / 48;
        float acc = fb[o];
        #pragma unroll 4
        for (int w = 0; w < 200; w++)
            acc = fmaf(b2f(row[w * 48 + c]), fwT[o * 200 + w], acc);
        out[(((size_t)b * 48 + c) * HH + hh) * 10 + o] = acc;
    }
}

// ---------------- host ----------------

static inline int imin(int a, int b) { return a < b ? a : b; }

extern "C" void kernel_launch(void* const* d_in, const int* in_sizes, int n_in,
                              void* d_out, int out_size, void* d_ws, size_t ws_size,
                              hipStream_t stream)
{
    const float* x   = (const float*)d_in[0];
    const float* w0  = (const float*)d_in[1];
    const float* b0  = (const float*)d_in[2];
    const float* bng = (const float*)d_in[3];
    const float* bnb = (const float*)d_in[4];
    const float* w1  = (const float*)d_in[5];
    const float* w2  = (const float*)d_in[6];
    const float* g1  = (const float*)d_in[7];
    const float* be1 = (const float*)d_in[8];
    const float* g2  = (const float*)d_in[9];
    const float* be2 = (const float*)d_in[10];
    const float* g3  = (const float*)d_in[11];
    const float* be3 = (const float*)d_in[12];
    const float* fcw = (const float*)d_in[13];
    const float* fcb = (const float*)d_in[14];
    float* out = (float*)d_out;

    bf16_t* h    = (bf16_t*)d_ws;           // SLOT    (NHWC)
    bf16_t* zcur = h + (size_t)SLOT;        // SLOT
    bf16_t* y64  = zcur + (size_t)SLOT;     // Y64SZ
    bf16_t* Fb   = y64 + (size_t)Y64SZ;     // 5*SLOT
    bf16_t* Gb   = Fb + 5 * (size_t)SLOT;   // 5*SLOT
    double* dstats = (double*)((char*)d_ws + BIGELEMS * 2);  // 9696 dbl: BN 96 + 25*384
    double* gram   = dstats + 9696;                          // 200 dbl
    float*  alpha  = (float*)(gram + 200);                   // 40 f
    bf16_t* apk1   = (bf16_t*)(alpha + 40);                  // 27648
    bf16_t* apk2   = apk1 + 27648;                           // 36864
    float*  scratch = (float*)Gb;  // conv0 raw fp32 (G region dead at that point)

    const size_t need = BIGELEMS * 2 + 9696 * 8 + 200 * 8 + 40 * 4 + (27648 + 36864) * 2;
    if (ws_size < need) return;

    const dim3 blk(256);
    const int SLOT_QBLK = SLOT / 4 / 256;       // 9600
    const int CHUNKS16  = SLOT * 2 / 16 / 256;  // 4800
    const int NB = 100, PXB = HWSZ / NB;        // 256 px per stats block

    zero_kernel<<<(19792 + 255) / 256, blk, 0, stream>>>((float*)dstats, 19792);
    pack_kernel<<<108, blk, 0, stream>>>(w1, apk1, 48, 64, 27648);
    pack_kernel<<<144, blk, 0, stream>>>(w2, apk2, 64, 48, 36864);
    fill16_kernel<<<CHUNKS16, blk, 0, stream>>>((float4*)zcur);

    // h = BN(conv0(x)+b0) in NHWC bf16
    conv0_kernel<<<BB * HWSZ / 4, dim3(192), 0, stream>>>(x, w0, b0, scratch);
    stats_kernel<48, 1, 48, 0, float><<<dim3(NB, BB), dim3(192), 0, stream>>>(scratch, dstats, PXB);
    bn_apply_kernel<<<SLOT / 1024, blk, 0, stream>>>(scratch, h, bng, bnb, dstats);

    int call = 0;
    auto resnet = [&](const bf16_t* zin, bf16_t* Fdst, bf16_t* Gdst) {
        double* ds = dstats + 96 + 384 * call;  // ds1 = +0 (64 pairs), ds2 = +128, ds3 = +256
        call++;
        dim3 cg(7, 32, BB);
        conv_mfma_kernel<48, 52, 64, true, false, false><<<cg, blk, 0, stream>>>(
            zin, (const s8v*)apk1, nullptr, y64, nullptr, nullptr, nullptr);
        stats_kernel<64, 8, 8, 8, bf16_t><<<dim3(NB, BB), blk, 0, stream>>>(y64, ds, PXB);
        conv_mfma_kernel<64, 68, 48, false, true, true><<<cg, blk, 0, stream>>>(
            y64, (const s8v*)apk2, h, Fdst, ds, g1, be1);
        stats_kernel<48, 6, 8, 8, bf16_t><<<dim3(NB, BB), dim3(192), 0, stream>>>(Fdst, ds + 128, PXB);
        add_relu_gn2_kernel<<<dim3(NB, BB), dim3(192), 0, stream>>>(
            Fdst, zin, ds + 128, g2, be2, ds + 256, PXB);
        gn3_apply_kernel<<<SLOT / 2048, blk, 0, stream>>>(Fdst, zin, Fdst, Gdst, ds + 256, g3, be3);
    };

    // slot 0: X=0, F0=f(0), G0=F0
    resnet(zcur, Fb, Gb);
    gram_zero_kernel<<<1, 64, 0, stream>>>(gram, 0, 1);
    gram_update_kernel<<<dim3(75, 8), blk, 0, stream>>>(Gb, gram, 0, 1);

    // slot 1: X=F0, F1=f(F0), G1=F1-F0
    copy16_kernel<<<CHUNKS16, blk, 0, stream>>>((float4*)zcur, (const float4*)Fb);
    resnet(zcur, Fb + (size_t)SLOT, Gb + (size_t)SLOT);
    gram_zero_kernel<<<1, 64, 0, stream>>>(gram, 1, 2);
    gram_update_kernel<<<dim3(75, 8), blk, 0, stream>>>(Gb, gram, 1, 2);

    for (int k = 2; k <= 24; k++) {
        int n = imin(k, 5);
        int j = k % 5;
        int nf = imin(k + 1, 5);
        solve_kernel<<<1, 64, 0, stream>>>(gram, alpha, n);
        xk_kernel<<<SLOT_QBLK, blk, 0, stream>>>(Fb, alpha, zcur, n, gram, j, nf);
        if (k < 24) {  // reference computes Fv at k=24 but never uses it
            resnet(zcur, Fb + (size_t)j * SLOT, Gb + (size_t)j * SLOT);
            gram_update_kernel<<<dim3(75, 8), blk, 0, stream>>>(Gb, gram, j, nf);
        }
    }

    // z_star = zcur; one extra f application into F slot 0 (no G)
    resnet(zcur, Fb, nullptr);

    // final linear: NHWC [8,128,200,48] x fw[10,200] -> out [8,48,128,10]
    fc_kernel<<<BB * HH, dim3(512), 0, stream>>>(Fb, fcw, fcb, out);
}